// Round 6
// baseline (637.538 us; speedup 1.0000x reference)
//
#include <hip/hip_runtime.h>
#include <math.h>

#define B_ 8
#define T_ 1024
#define S_ 1024
#define D_ 256
#define H_ 4
#define DH_ 64
#define AUDIO_ 768
#define MOTION_ 33
#define PERIOD_ 30
#define WIN_ 4
#define M_ (B_ * T_)  // 8192 rows for [B*T, D]-shaped activations

typedef _Float16 half8 __attribute__((ext_vector_type(8)));  // 8 fp16 (4 VGPRs)
typedef _Float16 half4 __attribute__((ext_vector_type(4)));
typedef __attribute__((ext_vector_type(4))) float f32x4;

// ---------------------------------------------------------------------------
// fp16-MFMA GEMM: C[m,n] = A[m,:] . W[n,:] + bias[n]  (optional ReLU)
// A: [M,K] fp32, W: [N,K] fp32. M%128==0, N%64==0, K%32==0.
// Block 256 thr = 4 waves (2x2), tile 128x64, BK=32, wave sub-tile 64x32:
// 8 MFMA per wave per barrier pair (2x the 64x64 tile) while grid stays
// >=256 blocks at N=256 (128x64 grid -> 64x4).
// ---------------------------------------------------------------------------
__global__ __launch_bounds__(256) void gemm_mfma(
    const float* __restrict__ A, const float* __restrict__ W,
    const float* __restrict__ bias, float* __restrict__ C,
    int M, int N, int K, int relu) {
  __shared__ _Float16 As[128][40];  // 40 = BK(32) + 8 pad (80 B row stride)
  __shared__ _Float16 Bs[64][40];
  const int tid = threadIdx.x;
  const int wave = tid >> 6, lane = tid & 63;
  const int wr = wave >> 1, wc = wave & 1;   // wave row (64), wave col (32)
  const int lr16 = lane & 15, kq = lane >> 4;
  const int bm = blockIdx.x, bn = blockIdx.y;

  f32x4 acc[4][2] = {};

  for (int k0 = 0; k0 < K; k0 += 32) {
    // stage A: 128 rows x 32k = 512 b128 writes (2/thread)
#pragma unroll
    for (int j = 0; j < 2; ++j) {
      const int i = tid + j * 256;
      const int r = i >> 2, sq = i & 3;
      const float* ap = A + (size_t)(bm * 128 + r) * K + k0 + sq * 8;
      const float4 a0 = *reinterpret_cast<const float4*>(ap);
      const float4 a1 = *reinterpret_cast<const float4*>(ap + 4);
      half8 pa;
      pa[0] = (_Float16)a0.x; pa[1] = (_Float16)a0.y;
      pa[2] = (_Float16)a0.z; pa[3] = (_Float16)a0.w;
      pa[4] = (_Float16)a1.x; pa[5] = (_Float16)a1.y;
      pa[6] = (_Float16)a1.z; pa[7] = (_Float16)a1.w;
      *reinterpret_cast<half8*>(&As[r][sq * 8]) = pa;
    }
    // stage B: 64 rows x 32k = 256 b128 writes (1/thread)
    {
      const int r = tid >> 2, sq = tid & 3;
      const float* wp = W + (size_t)(bn * 64 + r) * K + k0 + sq * 8;
      const float4 w0 = *reinterpret_cast<const float4*>(wp);
      const float4 w1 = *reinterpret_cast<const float4*>(wp + 4);
      half8 pw;
      pw[0] = (_Float16)w0.x; pw[1] = (_Float16)w0.y;
      pw[2] = (_Float16)w0.z; pw[3] = (_Float16)w0.w;
      pw[4] = (_Float16)w1.x; pw[5] = (_Float16)w1.y;
      pw[6] = (_Float16)w1.z; pw[7] = (_Float16)w1.w;
      *reinterpret_cast<half8*>(&Bs[r][sq * 8]) = pw;
    }
    __syncthreads();
    half8 af[4], bf[2];
#pragma unroll
    for (int m = 0; m < 4; ++m)
      af[m] = *reinterpret_cast<const half8*>(&As[wr * 64 + m * 16 + lr16][kq * 8]);
#pragma unroll
    for (int n = 0; n < 2; ++n)
      bf[n] = *reinterpret_cast<const half8*>(&Bs[wc * 32 + n * 16 + lr16][kq * 8]);
#pragma unroll
    for (int m = 0; m < 4; ++m)
#pragma unroll
      for (int n = 0; n < 2; ++n)
        acc[m][n] = __builtin_amdgcn_mfma_f32_16x16x32_f16(af[m], bf[n], acc[m][n], 0, 0, 0);
    __syncthreads();
  }

  // epilogue: C/D layout col=lane&15, row=(lane>>4)*4+reg
#pragma unroll
  for (int m = 0; m < 4; ++m) {
#pragma unroll
    for (int n = 0; n < 2; ++n) {
      const int col = bn * 64 + wc * 32 + n * 16 + lr16;
      const float bv = bias[col];
#pragma unroll
      for (int j = 0; j < 4; ++j) {
        const int row = bm * 128 + wr * 64 + m * 16 + kq * 4 + j;
        float v = acc[m][n][j] + bv;
        if (relu) v = fmaxf(v, 0.f);
        C[(size_t)row * N + col] = v;
      }
    }
  }
}

// ---------------------------------------------------------------------------
// fp16-MFMA Conv1d k=5 pad=2 over [B,S,D] (channels innermost).
// Stage-once-reuse-5x: per 32-ch block, stage X rows s0-2..s0+65 and all
// 5 tap weight slices, then 5 taps x 4 MFMA per wave between one barrier
// pair (20 MFMA / stage round; 8 rounds total vs 40 in the naive version).
// grid (M/64, D/64); batch = blockIdx.x>>4. mode 0: gelu; mode 1: residual.
// ---------------------------------------------------------------------------
__global__ __launch_bounds__(256) void conv_mfma(
    const float* __restrict__ X, const float* __restrict__ W,
    const float* __restrict__ bias, float* Y, int mode) {
  __shared__ _Float16 Xs[68][40];        // row r = position s0+r-2, 32 ch
  __shared__ _Float16 Ws5[5][64][40];    // [tap][oc][ch]
  const int tid = threadIdx.x;
  const int wave = tid >> 6, lane = tid & 63;
  const int wr = wave >> 1, wc = wave & 1;
  const int lr16 = lane & 15, kq = lane >> 4;
  const int b = blockIdx.x >> 4;
  const int s0 = (blockIdx.x & 15) * 64;
  const int o0 = blockIdx.y * 64;

  f32x4 acc[2][2] = {};

  for (int c0 = 0; c0 < D_; c0 += 32) {
    // stage X: 68 rows x 4 quarters
    for (int i = tid; i < 68 * 4; i += 256) {
      const int r = i >> 2, sq = i & 3;
      const int s = s0 + r - 2;
      half8 pa = {};
      if (s >= 0 && s < S_) {
        const float* xp = X + ((size_t)b * S_ + s) * D_ + c0 + sq * 8;
        const float4 a0 = *reinterpret_cast<const float4*>(xp);
        const float4 a1 = *reinterpret_cast<const float4*>(xp + 4);
        pa[0] = (_Float16)a0.x; pa[1] = (_Float16)a0.y;
        pa[2] = (_Float16)a0.z; pa[3] = (_Float16)a0.w;
        pa[4] = (_Float16)a1.x; pa[5] = (_Float16)a1.y;
        pa[6] = (_Float16)a1.z; pa[7] = (_Float16)a1.w;
      }
      *reinterpret_cast<half8*>(&Xs[r][sq * 8]) = pa;
    }
    // stage W: 5 taps x 64 oc x 4 quarters = 1280 (5/thread)
    for (int i = tid; i < 5 * 64 * 4; i += 256) {
      const int t = i >> 8, rem = i & 255, oc = rem >> 2, sq = rem & 3;
      const float* wp = W + ((size_t)(o0 + oc) * D_ + c0 + sq * 8) * 5 + t;
      half8 pw;
      pw[0] = (_Float16)wp[0];  pw[1] = (_Float16)wp[5];
      pw[2] = (_Float16)wp[10]; pw[3] = (_Float16)wp[15];
      pw[4] = (_Float16)wp[20]; pw[5] = (_Float16)wp[25];
      pw[6] = (_Float16)wp[30]; pw[7] = (_Float16)wp[35];
      *reinterpret_cast<half8*>(&Ws5[t][oc][sq * 8]) = pw;
    }
    __syncthreads();
#pragma unroll
    for (int t = 0; t < 5; ++t) {
      half8 af[2], bf[2];
#pragma unroll
      for (int m = 0; m < 2; ++m)
        af[m] = *reinterpret_cast<const half8*>(&Xs[wr * 32 + m * 16 + lr16 + t][kq * 8]);
#pragma unroll
      for (int n = 0; n < 2; ++n)
        bf[n] = *reinterpret_cast<const half8*>(&Ws5[t][wc * 32 + n * 16 + lr16][kq * 8]);
#pragma unroll
      for (int m = 0; m < 2; ++m)
#pragma unroll
        for (int n = 0; n < 2; ++n)
          acc[m][n] = __builtin_amdgcn_mfma_f32_16x16x32_f16(af[m], bf[n], acc[m][n], 0, 0, 0);
    }
    __syncthreads();
  }

#pragma unroll
  for (int m = 0; m < 2; ++m) {
#pragma unroll
    for (int n = 0; n < 2; ++n) {
      const int oc = o0 + wc * 32 + n * 16 + lr16;
      const float bv = bias[oc];
#pragma unroll
      for (int j = 0; j < 4; ++j) {
        const int s = s0 + wr * 32 + m * 16 + kq * 4 + j;
        float* yp = Y + ((size_t)b * S_ + s) * D_ + oc;
        float v = acc[m][n][j] + bv;
        if (mode == 0) {
          v = 0.5f * v * (1.f + erff(v * 0.70710678118654752f));
          *yp = v;
        } else {
          *yp += v;
        }
      }
    }
  }
}

// ---------------------------------------------------------------------------
// x = shifted_motion @ W_vm.T + b_vm + PE(t%30)
// ---------------------------------------------------------------------------
__global__ __launch_bounds__(256) void motion_pe(
    const float* __restrict__ TM, const float* __restrict__ Wvm,
    const float* __restrict__ bvm, float* __restrict__ Xout) {
  const int d = threadIdx.x;
  const int bt = blockIdx.x;
  const int t = bt & (T_ - 1);
  const int b = bt >> 10;
  float acc = bvm[d];
  if (t > 0) {
    const float* mrow = TM + ((size_t)b * T_ + t - 1) * MOTION_;
    const float* wrow = Wvm + (size_t)d * MOTION_;
#pragma unroll
    for (int m = 0; m < MOTION_; ++m) acc += mrow[m] * wrow[m];
  }
  const int pos = t % PERIOD_;
  const int i2 = d >> 1;
  const float div = expf((float)(2 * i2) * (-9.210340371976184f / 256.f));
  const float ang = (float)pos * div;
  acc += (d & 1) ? cosf(ang) : sinf(ang);
  Xout[(size_t)bt * D_ + d] = acc;
}

// ---------------------------------------------------------------------------
// MFMA self-attention (fp16 operands, fp32 accum), swapped-QK^T layout.
// (unchanged from round 5 — verified passing)
// ---------------------------------------------------------------------------
#define RS_ 72  // fp16 row stride (64 + 8 pad), 144 B
__global__ __launch_bounds__(256) void self_attn(
    const float* __restrict__ QKV, float* __restrict__ O) {
  __shared__ _Float16 Ks[64 * RS_];
  __shared__ _Float16 VTs[64 * RS_];
  __shared__ _Float16 Ps[4][16 * RS_];
  const int qt = blockIdx.x, h = blockIdx.y, b = blockIdx.z;
  const int tid = threadIdx.x;
  const int wave = tid >> 6, lane = tid & 63;
  const int lo = lane & 15, hi = lane >> 4;
  const float slope = exp2f(-2.f * (float)(h + 1));
  const int qloc = wave * 16 + lo;
  const int tq = qt * 64 + qloc;
  const size_t base = (size_t)b * T_ * 768 + h * 64;

  half8 qf[2];
#pragma unroll
  for (int s = 0; s < 2; ++s) {
    const float* qp = QKV + base + (size_t)(qt * 64 + qloc) * 768 + s * 32 + hi * 8;
    const float4 q0 = *reinterpret_cast<const float4*>(qp);
    const float4 q1 = *reinterpret_cast<const float4*>(qp + 4);
    qf[s][0] = (_Float16)q0.x; qf[s][1] = (_Float16)q0.y;
    qf[s][2] = (_Float16)q0.z; qf[s][3] = (_Float16)q0.w;
    qf[s][4] = (_Float16)q1.x; qf[s][5] = (_Float16)q1.y;
    qf[s][6] = (_Float16)q1.z; qf[s][7] = (_Float16)q1.w;
  }

  f32x4 oacc[4] = {};
  float mrun = -1e30f, lrun = 0.f;

  for (int kt = 0; kt <= qt; ++kt) {
    __syncthreads();
    for (int c = tid; c < 512; c += 256) {
      const int j = c >> 3, ch = c & 7;
      const size_t rowoff = base + (size_t)(kt * 64 + j) * 768;
      {
        const float* kp = QKV + rowoff + 256 + ch * 8;
        const float4 k0 = *reinterpret_cast<const float4*>(kp);
        const float4 k1 = *reinterpret_cast<const float4*>(kp + 4);
        half8 hk;
        hk[0] = (_Float16)k0.x; hk[1] = (_Float16)k0.y;
        hk[2] = (_Float16)k0.z; hk[3] = (_Float16)k0.w;
        hk[4] = (_Float16)k1.x; hk[5] = (_Float16)k1.y;
        hk[6] = (_Float16)k1.z; hk[7] = (_Float16)k1.w;
        *reinterpret_cast<half8*>(&Ks[j * RS_ + ch * 8]) = hk;
      }
      {
        const float* vp = QKV + rowoff + 512 + ch * 8;
        const float4 v0 = *reinterpret_cast<const float4*>(vp);
        const float4 v1 = *reinterpret_cast<const float4*>(vp + 4);
        float vv[8] = {v0.x, v0.y, v0.z, v0.w, v1.x, v1.y, v1.z, v1.w};
#pragma unroll
        for (int r = 0; r < 8; ++r) {
          const int d = ch * 8 + r;
          const int sw = ((d & 7) ^ (d >> 3)) << 3;
          VTs[d * RS_ + (j ^ sw)] = (_Float16)vv[r];
        }
      }
    }
    __syncthreads();

    f32x4 st[4] = {};
#pragma unroll
    for (int f = 0; f < 4; ++f) {
#pragma unroll
      for (int s = 0; s < 2; ++s) {
        const half8 kf = *reinterpret_cast<const half8*>(
            &Ks[(f * 16 + lo) * RS_ + s * 32 + hi * 8]);
        st[f] = __builtin_amdgcn_mfma_f32_16x16x32_f16(kf, qf[s], st[f], 0, 0, 0);
      }
    }

    float sc[4][4];
    float tmax = -1e30f;
#pragma unroll
    for (int f = 0; f < 4; ++f)
#pragma unroll
      for (int r = 0; r < 4; ++r) {
        const int j = kt * 64 + f * 16 + hi * 4 + r;
        const int rel = tq - j;
        const float v = (rel >= 0)
            ? st[f][r] * 0.125f - slope * (float)(rel / PERIOD_) : -1e30f;
        sc[f][r] = v;
        tmax = fmaxf(tmax, v);
      }
    tmax = fmaxf(tmax, __shfl_xor(tmax, 16, 64));
    tmax = fmaxf(tmax, __shfl_xor(tmax, 32, 64));
    const float mnew = fmaxf(mrun, tmax);
    const float scale = __expf(mrun - mnew);

    float psum = 0.f;
#pragma unroll
    for (int f = 0; f < 4; ++f) {
      half4 ph;
#pragma unroll
      for (int r = 0; r < 4; ++r) {
        const float p = __expf(sc[f][r] - mnew);
        psum += p;
        ph[r] = (_Float16)p;
      }
      *reinterpret_cast<half4*>(&Ps[wave][lo * RS_ + f * 16 + hi * 4]) = ph;
    }
    psum += __shfl_xor(psum, 16, 64);
    psum += __shfl_xor(psum, 32, 64);
    lrun = lrun * scale + psum;
    mrun = mnew;

    float rsc[4];
#pragma unroll
    for (int r = 0; r < 4; ++r) rsc[r] = __shfl(scale, hi * 4 + r, 64);
#pragma unroll
    for (int nf = 0; nf < 4; ++nf)
#pragma unroll
      for (int r = 0; r < 4; ++r) oacc[nf][r] *= rsc[r];

#pragma unroll
    for (int s = 0; s < 2; ++s) {
      const half8 pf = *reinterpret_cast<const half8*>(
          &Ps[wave][lo * RS_ + s * 32 + hi * 8]);
#pragma unroll
      for (int nf = 0; nf < 4; ++nf) {
        const int d = nf * 16 + lo;
        const int sw = ((d & 7) ^ (d >> 3)) << 3;
        const half8 vf = *reinterpret_cast<const half8*>(
            &VTs[d * RS_ + ((s * 32 + hi * 8) ^ sw)]);
        oacc[nf] = __builtin_amdgcn_mfma_f32_16x16x32_f16(pf, vf, oacc[nf], 0, 0, 0);
      }
    }
  }

  float invl[4];
#pragma unroll
  for (int r = 0; r < 4; ++r) invl[r] = 1.f / __shfl(lrun, hi * 4 + r, 64);
#pragma unroll
  for (int nf = 0; nf < 4; ++nf)
#pragma unroll
    for (int r = 0; r < 4; ++r) {
      const int q = qt * 64 + wave * 16 + hi * 4 + r;
      O[((size_t)b * T_ + q) * D_ + h * 64 + nf * 16 + lo] = oacc[nf][r] * invl[r];
    }
}

// ---------------------------------------------------------------------------
// Cross-attention with band mask |t-j|<=4. Q: [B*T,256], KV: [B*S,512] (k|v).
// One thread per (b,t,h); at most 9 keys, softmax fully in registers.
// ---------------------------------------------------------------------------
__global__ __launch_bounds__(256) void cross_attn(
    const float* __restrict__ Q, const float* __restrict__ KV,
    float* __restrict__ O) {
  const int gid = blockIdx.x * 256 + threadIdx.x;  // 0 .. B*T*H-1
  const int h = gid & 3;
  const int bt = gid >> 2;
  const int t = bt & (T_ - 1);
  const int b = bt >> 10;

  float q[64];
  const float* qp = Q + (size_t)bt * D_ + h * 64;
#pragma unroll
  for (int d0 = 0; d0 < 64; d0 += 4) {
    const float4 v = *reinterpret_cast<const float4*>(qp + d0);
    q[d0] = v.x; q[d0 + 1] = v.y; q[d0 + 2] = v.z; q[d0 + 3] = v.w;
  }

  const int j0 = (t - WIN_ > 0) ? t - WIN_ : 0;
  const int j1 = (t + WIN_ < S_ - 1) ? t + WIN_ : S_ - 1;
  const int nj = j1 - j0 + 1;

  float sc[9];
  float mx = -1e30f;
#pragma unroll
  for (int jj = 0; jj < 9; ++jj) {
    if (jj < nj) {
      const float* kp = KV + ((size_t)b * S_ + j0 + jj) * 512 + h * 64;
      float s = 0.f;
#pragma unroll
      for (int d0 = 0; d0 < 64; d0 += 4) {
        const float4 kv = *reinterpret_cast<const float4*>(kp + d0);
        s += q[d0] * kv.x + q[d0 + 1] * kv.y + q[d0 + 2] * kv.z + q[d0 + 3] * kv.w;
      }
      sc[jj] = s * 0.125f;
      mx = fmaxf(mx, sc[jj]);
    } else {
      sc[jj] = -1e30f;
    }
  }
  float l = 0.f;
  float p[9];
#pragma unroll
  for (int jj = 0; jj < 9; ++jj) { p[jj] = __expf(sc[jj] - mx); l += p[jj]; }
  const float inv = 1.f / l;

  float o[64];
#pragma unroll
  for (int d = 0; d < 64; ++d) o[d] = 0.f;
#pragma unroll
  for (int jj = 0; jj < 9; ++jj) {
    if (jj < nj) {
      const float pj = p[jj] * inv;
      const float* vp = KV + ((size_t)b * S_ + j0 + jj) * 512 + 256 + h * 64;
#pragma unroll
      for (int d0 = 0; d0 < 64; d0 += 4) {
        const float4 vv = *reinterpret_cast<const float4*>(vp + d0);
        o[d0] += pj * vv.x; o[d0 + 1] += pj * vv.y;
        o[d0 + 2] += pj * vv.z; o[d0 + 3] += pj * vv.w;
      }
    }
  }
  float* op = O + (size_t)bt * D_ + h * 64;
#pragma unroll
  for (int d = 0; d < 64; ++d) op[d] = o[d];
}

// ---------------------------------------------------------------------------
// Out = LayerNorm(X + R) * g + b.   One wave per 256-wide row. Out may == X.
// ---------------------------------------------------------------------------
__global__ __launch_bounds__(256) void ln_res(
    const float* X, const float* __restrict__ R,
    const float* __restrict__ g, const float* __restrict__ bta, float* Out) {
  const int wid = threadIdx.x >> 6, lane = threadIdx.x & 63;
  const size_t row = (size_t)blockIdx.x * 4 + wid;
  const float* xp = X + row * D_;
  const float* rp = R + row * D_;
  float v[4];
  float s = 0.f;
#pragma unroll
  for (int k = 0; k < 4; ++k) {
    const int d = lane + k * 64;
    v[k] = xp[d] + rp[d];
    s += v[k];
  }
#pragma unroll
  for (int off = 32; off; off >>= 1) s += __shfl_xor(s, off, 64);
  const float mu = s * (1.f / 256.f);
  float var = 0.f;
#pragma unroll
  for (int k = 0; k < 4; ++k) { const float d = v[k] - mu; var += d * d; }
#pragma unroll
  for (int off = 32; off; off >>= 1) var += __shfl_xor(var, off, 64);
  const float rs = rsqrtf(var * (1.f / 256.f) + 1e-5f);
#pragma unroll
  for (int k = 0; k < 4; ++k) {
    const int d = lane + k * 64;
    Out[row * D_ + d] = (v[k] - mu) * rs * g[d] + bta[d];
  }
}

// ---------------------------------------------------------------------------
// out = clip(x @ W_vr.T + b_vr, 0, 1).  One thread per (row, j<33).
// ---------------------------------------------------------------------------
__global__ __launch_bounds__(256) void head_clip(
    const float* __restrict__ X, const float* __restrict__ Wv,
    const float* __restrict__ bv, float* __restrict__ Out) {
  const int gid = blockIdx.x * 256 + threadIdx.x;
  if (gid >= M_ * MOTION_) return;
  const int j = gid % MOTION_;
  const int row = gid / MOTION_;
  const float4* xr = reinterpret_cast<const float4*>(X + (size_t)row * D_);
  const float4* wr = reinterpret_cast<const float4*>(Wv + (size_t)j * D_);
  float acc = bv[j];
#pragma unroll
  for (int i = 0; i < 64; ++i) {
    const float4 a = xr[i], w = wr[i];
    acc += a.x * w.x + a.y * w.y + a.z * w.z + a.w * w.w;
  }
  Out[gid] = fminf(fmaxf(acc, 0.f), 1.f);
}

// ---------------------------------------------------------------------------
extern "C" void kernel_launch(void* const* d_in, const int* in_sizes, int n_in,
                              void* d_out, int out_size, void* d_ws, size_t ws_size,
                              hipStream_t stream) {
  (void)in_sizes; (void)n_in; (void)out_size; (void)ws_size;
  const float* hidden = (const float*)d_in[0];
  const float* tmot   = (const float*)d_in[1];
  const float* W_af   = (const float*)d_in[2];
  const float* b_af   = (const float*)d_in[3];
  const float* c1w    = (const float*)d_in[4];
  const float* c1b    = (const float*)d_in[5];
  const float* c2w    = (const float*)d_in[6];
  const float* c2b    = (const float*)d_in[7];
  const float* Wvm    = (const float*)d_in[8];
  const float* bvm    = (const float*)d_in[9];
  const float* sa_in_w  = (const float*)d_in[10];
  const float* sa_in_b  = (const float*)d_in[11];
  const float* sa_out_w = (const float*)d_in[12];
  const float* sa_out_b = (const float*)d_in[13];
  const float* ca_in_w  = (const float*)d_in[14];
  const float* ca_in_b  = (const float*)d_in[15];
  const float* ca_out_w = (const float*)d_in[16];
  const float* ca_out_b = (const float*)d_in[17];
  const float* ln1g = (const float*)d_in[18];
  const float* ln1b = (const float*)d_in[19];
  const float* ln2g = (const float*)d_in[20];
  const float* ln2b = (const float*)d_in[21];
  const float* ln3g = (const float*)d_in[22];
  const float* ln3b = (const float*)d_in[23];
  const float* ff1w = (const float*)d_in[24];
  const float* ff1b = (const float*)d_in[25];
  const float* ff2w = (const float*)d_in[26];
  const float* ff2b = (const float*)d_in[27];
  const float* Wvr  = (const float*)d_in[28];
  const float* bvr  = (const float*)d_in[29];
  float* out = (float*)d_out;

  float* ws = (float*)d_ws;
  const size_t BSD = (size_t)B_ * T_ * D_;  // 2,097,152 floats
  float* audio = ws;            // [B*S, 256]
  float* x     = ws + BSD;      // [B*T, 256]
  float* att   = ws + 2 * BSD;  // [B*T, 256]
  float* t1    = ws + 3 * BSD;  // [B*T, 256] scratch (conv1 output)
  float* qkv   = ws + 4 * BSD;  // [B*T, 768] / reused for q, kv, ffn hidden

  const dim3 blk(256);

  // audio front-end
  gemm_mfma<<<dim3(M_ / 128, D_ / 64), blk, 0, stream>>>(hidden, W_af, b_af, audio, M_, D_, AUDIO_, 0);
  conv_mfma<<<dim3(M_ / 64, D_ / 64), blk, 0, stream>>>(audio, c1w, c1b, t1, 0);
  conv_mfma<<<dim3(M_ / 64, D_ / 64), blk, 0, stream>>>(t1, c2w, c2b, audio, 1);

  // motion embedding + PE
  motion_pe<<<dim3(M_), blk, 0, stream>>>(tmot, Wvm, bvm, x);

  for (int l = 0; l < 2; ++l) {
    // self-attention
    gemm_mfma<<<dim3(M_ / 128, 768 / 64), blk, 0, stream>>>(
        x, sa_in_w + (size_t)l * 768 * 256, sa_in_b + l * 768, qkv, M_, 768, 256, 0);
    self_attn<<<dim3(T_ / 64, H_, B_), blk, 0, stream>>>(qkv, att);
    gemm_mfma<<<dim3(M_ / 128, 256 / 64), blk, 0, stream>>>(
        att, sa_out_w + (size_t)l * 256 * 256, sa_out_b + l * 256, t1, M_, 256, 256, 0);
    ln_res<<<dim3(M_ / 4), blk, 0, stream>>>(x, t1, ln1g + l * 256, ln1b + l * 256, x);

    // cross-attention (banded)
    gemm_mfma<<<dim3(M_ / 128, 256 / 64), blk, 0, stream>>>(
        x, ca_in_w + (size_t)l * 768 * 256, ca_in_b + l * 768, qkv, M_, 256, 256, 0);
    gemm_mfma<<<dim3(M_ / 128, 512 / 64), blk, 0, stream>>>(
        audio, ca_in_w + (size_t)l * 768 * 256 + 256 * 256, ca_in_b + l * 768 + 256,
        qkv + BSD, M_, 512, 256, 0);
    cross_attn<<<dim3(M_ * H_ / 256), blk, 0, stream>>>(qkv, qkv + BSD, att);
    gemm_mfma<<<dim3(M_ / 128, 256 / 64), blk, 0, stream>>>(
        att, ca_out_w + (size_t)l * 256 * 256, ca_out_b + l * 256, t1, M_, 256, 256, 0);
    ln_res<<<dim3(M_ / 4), blk, 0, stream>>>(x, t1, ln2g + l * 256, ln2b + l * 256, x);

    // FFN
    gemm_mfma<<<dim3(M_ / 128, 512 / 64), blk, 0, stream>>>(
        x, ff1w + (size_t)l * 512 * 256, ff1b + l * 512, qkv, M_, 512, 256, 1);
    gemm_mfma<<<dim3(M_ / 128, 256 / 64), blk, 0, stream>>>(
        qkv, ff2w + (size_t)l * 256 * 512, ff2b + l * 256, t1, M_, 256, 512, 0);
    ln_res<<<dim3(M_ / 4), blk, 0, stream>>>(x, t1, ln3g + l * 256, ln3b + l * 256, x);
  }

  head_clip<<<dim3((M_ * MOTION_ + 255) / 256), blk, 0, stream>>>(x, Wvr, bvr, out);
}

// Round 7
// 426.140 us; speedup vs baseline: 1.4961x; 1.4961x over previous
//
#include <hip/hip_runtime.h>
#include <math.h>

#define B_ 8
#define T_ 1024
#define S_ 1024
#define D_ 256
#define H_ 4
#define DH_ 64
#define AUDIO_ 768
#define MOTION_ 33
#define PERIOD_ 30
#define WIN_ 4
#define M_ (B_ * T_)

typedef _Float16 half8 __attribute__((ext_vector_type(8)));
typedef _Float16 half4 __attribute__((ext_vector_type(4)));
typedef __attribute__((ext_vector_type(4))) float f32x4;

// fp16 weight arena offsets (halves)
#define O_AF    0
#define O_SAIN  196608   // + l*196608
#define O_SAOUT 589824   // + l*65536
#define O_CAIN  720896   // + l*196608
#define O_CAOUT 1114112  // + l*65536
#define O_FF1   1245184  // + l*131072
#define O_FF2   1507328  // + l*131072
#define O_CONV1 1769472
#define O_CONV2 2097152
#define WH_TOT  2424832
#define HID_TOT 6291456  // 8192*768

struct CvtSrc { const float* p[16]; };

// ---------------------------------------------------------------------------
// One-shot fp32->fp16 conversion of all weights (+ conv repack to
// [oc][tap*256+cin]) and the hidden_states input. Single launch.
// ---------------------------------------------------------------------------
__global__ __launch_bounds__(256) void cvt_all(
    CvtSrc s, _Float16* __restrict__ wH, _Float16* __restrict__ hidH) {
  const long i = (long)blockIdx.x * 256 + threadIdx.x;
  if (i >= (long)WH_TOT + HID_TOT) return;
  if (i >= WH_TOT) { const long j = i - WH_TOT; hidH[j] = (_Float16)s.p[15][j]; return; }
  if (i >= O_CONV2) {
    const long j = i - O_CONV2, oc = j / 1280, r = j % 1280, tap = r >> 8, cin = r & 255;
    wH[i] = (_Float16)s.p[14][(oc * 256 + cin) * 5 + tap]; return;
  }
  if (i >= O_CONV1) {
    const long j = i - O_CONV1, oc = j / 1280, r = j % 1280, tap = r >> 8, cin = r & 255;
    wH[i] = (_Float16)s.p[13][(oc * 256 + cin) * 5 + tap]; return;
  }
  int seg; long base;
  if      (i >= 1638400) { seg = 12; base = 1638400; }
  else if (i >= 1507328) { seg = 11; base = 1507328; }
  else if (i >= 1376256) { seg = 10; base = 1376256; }
  else if (i >= 1245184) { seg = 9;  base = 1245184; }
  else if (i >= 1179648) { seg = 8;  base = 1179648; }
  else if (i >= 1114112) { seg = 7;  base = 1114112; }
  else if (i >= 917504)  { seg = 6;  base = 917504; }
  else if (i >= 720896)  { seg = 5;  base = 720896; }
  else if (i >= 655360)  { seg = 4;  base = 655360; }
  else if (i >= 589824)  { seg = 3;  base = 589824; }
  else if (i >= 393216)  { seg = 2;  base = 393216; }
  else if (i >= 196608)  { seg = 1;  base = 196608; }
  else                   { seg = 0;  base = 0; }
  wH[i] = (_Float16)s.p[seg][i - base];
}

// ---------------------------------------------------------------------------
// fp16 GEMM: C = A @ W.T + bias. A [M,K] fp16, W [N,K] fp16.
// Tile 64x64, BK=32, 4 waves 2x2 (proven layout). Register prefetch of the
// next K-chunk hides global latency under ds_read+MFMA.
// Outputs: Cf (fp32, nullable), Ch (fp16 mirror, nullable), optional relu.
// ---------------------------------------------------------------------------
__global__ __launch_bounds__(256) void gemm_h(
    const _Float16* __restrict__ A, const _Float16* __restrict__ W,
    const float* __restrict__ bias, float* __restrict__ Cf,
    _Float16* __restrict__ Ch, int M, int N, int K, int relu) {
  __shared__ _Float16 As[64][40];
  __shared__ _Float16 Bs[64][40];
  const int tid = threadIdx.x;
  const int wave = tid >> 6, lane = tid & 63;
  const int wr = wave >> 1, wc = wave & 1;
  const int lr16 = lane & 15, kq = lane >> 4;
  const int bm = blockIdx.x, bn = blockIdx.y;
  const int sr = tid >> 2, sq = tid & 3;

  const _Float16* Ap = A + (size_t)(bm * 64 + sr) * K + sq * 8;
  const _Float16* Wp = W + (size_t)(bn * 64 + sr) * K + sq * 8;

  half8 ra = *reinterpret_cast<const half8*>(Ap);
  half8 rw = *reinterpret_cast<const half8*>(Wp);
  f32x4 acc[2][2] = {};

  for (int k0 = 0; k0 < K; k0 += 32) {
    __syncthreads();
    *reinterpret_cast<half8*>(&As[sr][sq * 8]) = ra;
    *reinterpret_cast<half8*>(&Bs[sr][sq * 8]) = rw;
    __syncthreads();
    if (k0 + 32 < K) {
      ra = *reinterpret_cast<const half8*>(Ap + k0 + 32);
      rw = *reinterpret_cast<const half8*>(Wp + k0 + 32);
    }
    half8 af[2], bf[2];
#pragma unroll
    for (int m = 0; m < 2; ++m)
      af[m] = *reinterpret_cast<const half8*>(&As[wr * 32 + m * 16 + lr16][kq * 8]);
#pragma unroll
    for (int n = 0; n < 2; ++n)
      bf[n] = *reinterpret_cast<const half8*>(&Bs[wc * 32 + n * 16 + lr16][kq * 8]);
#pragma unroll
    for (int m = 0; m < 2; ++m)
#pragma unroll
      for (int n = 0; n < 2; ++n)
        acc[m][n] = __builtin_amdgcn_mfma_f32_16x16x32_f16(af[m], bf[n], acc[m][n], 0, 0, 0);
  }

#pragma unroll
  for (int m = 0; m < 2; ++m) {
#pragma unroll
    for (int n = 0; n < 2; ++n) {
      const int col = bn * 64 + wc * 32 + n * 16 + lr16;
      const float bv = bias[col];
#pragma unroll
      for (int j = 0; j < 4; ++j) {
        const int row = bm * 64 + wr * 32 + m * 16 + kq * 4 + j;
        float v = acc[m][n][j] + bv;
        if (relu) v = fmaxf(v, 0.f);
        const size_t idx = (size_t)row * N + col;
        if (Cf) Cf[idx] = v;
        if (Ch) Ch[idx] = (_Float16)v;
      }
    }
  }
}

// ---------------------------------------------------------------------------
// Conv1d k=5 as fp16 GEMM with K=1280 (tap-major repacked weights).
// A row for position s = Xh[b, s-2 .. s+2, :] (contiguous!); batch-edge rows
// zeroed in registers. Tile 64x64, BK=32 (tap uniform per chunk), prefetch.
// mode 0: OutH = fp16(gelu(v));  mode 1: OutH = fp16(v + ResF) (residual).
// ---------------------------------------------------------------------------
__device__ __forceinline__ half8 conv_ld(const _Float16* Xb, int p, int tap, int cin) {
  const int sp = p + tap - 2;
  if (sp < 0 || sp >= S_) { half8 z = {}; return z; }
  return *reinterpret_cast<const half8*>(Xb + (size_t)sp * D_ + cin);
}

__global__ __launch_bounds__(256) void conv_h(
    const _Float16* __restrict__ Xh, const _Float16* __restrict__ Wc,
    const float* __restrict__ bias, _Float16* __restrict__ OutH,
    const float* __restrict__ ResF, int mode) {
  __shared__ _Float16 As[64][40];
  __shared__ _Float16 Bs[64][40];
  const int tid = threadIdx.x;
  const int wave = tid >> 6, lane = tid & 63;
  const int wr = wave >> 1, wc = wave & 1;
  const int lr16 = lane & 15, kq = lane >> 4;
  const int b = blockIdx.x >> 4;
  const int s0 = (blockIdx.x & 15) * 64;
  const int o0 = blockIdx.y * 64;
  const int sr = tid >> 2, sq = tid & 3;

  const _Float16* Xb = Xh + (size_t)b * S_ * D_;
  const _Float16* Wp = Wc + (size_t)(o0 + sr) * 1280 + sq * 8;
  const int p = s0 + sr;

  half8 ra = conv_ld(Xb, p, 0, sq * 8);
  half8 rw = *reinterpret_cast<const half8*>(Wp);
  f32x4 acc[2][2] = {};

  for (int k0 = 0; k0 < 1280; k0 += 32) {
    __syncthreads();
    *reinterpret_cast<half8*>(&As[sr][sq * 8]) = ra;
    *reinterpret_cast<half8*>(&Bs[sr][sq * 8]) = rw;
    __syncthreads();
    if (k0 + 32 < 1280) {
      const int kn = k0 + 32;
      ra = conv_ld(Xb, p, kn >> 8, (kn & 255) + sq * 8);
      rw = *reinterpret_cast<const half8*>(Wp + kn);
    }
    half8 af[2], bf[2];
#pragma unroll
    for (int m = 0; m < 2; ++m)
      af[m] = *reinterpret_cast<const half8*>(&As[wr * 32 + m * 16 + lr16][kq * 8]);
#pragma unroll
    for (int n = 0; n < 2; ++n)
      bf[n] = *reinterpret_cast<const half8*>(&Bs[wc * 32 + n * 16 + lr16][kq * 8]);
#pragma unroll
    for (int m = 0; m < 2; ++m)
#pragma unroll
      for (int n = 0; n < 2; ++n)
        acc[m][n] = __builtin_amdgcn_mfma_f32_16x16x32_f16(af[m], bf[n], acc[m][n], 0, 0, 0);
  }

#pragma unroll
  for (int m = 0; m < 2; ++m) {
#pragma unroll
    for (int n = 0; n < 2; ++n) {
      const int oc = o0 + wc * 32 + n * 16 + lr16;
      const float bv = bias[oc];
#pragma unroll
      for (int j = 0; j < 4; ++j) {
        const int s = s0 + wr * 32 + m * 16 + kq * 4 + j;
        const size_t idx = ((size_t)b * S_ + s) * D_ + oc;
        float v = acc[m][n][j] + bv;
        if (mode == 0) {
          v = 0.5f * v * (1.f + erff(v * 0.70710678118654752f));
        } else {
          v += ResF[idx];
        }
        OutH[idx] = (_Float16)v;
      }
    }
  }
}

// ---------------------------------------------------------------------------
// x = shifted_motion @ W_vm.T + b_vm + PE(t%30); writes fp32 + fp16 mirror.
// ---------------------------------------------------------------------------
__global__ __launch_bounds__(256) void motion_pe(
    const float* __restrict__ TM, const float* __restrict__ Wvm,
    const float* __restrict__ bvm, float* __restrict__ Xout,
    _Float16* __restrict__ XoutH) {
  const int d = threadIdx.x;
  const int bt = blockIdx.x;
  const int t = bt & (T_ - 1);
  const int b = bt >> 10;
  float acc = bvm[d];
  if (t > 0) {
    const float* mrow = TM + ((size_t)b * T_ + t - 1) * MOTION_;
    const float* wrow = Wvm + (size_t)d * MOTION_;
#pragma unroll
    for (int m = 0; m < MOTION_; ++m) acc += mrow[m] * wrow[m];
  }
  const int pos = t % PERIOD_;
  const int i2 = d >> 1;
  const float div = expf((float)(2 * i2) * (-9.210340371976184f / 256.f));
  const float ang = (float)pos * div;
  acc += (d & 1) ? cosf(ang) : sinf(ang);
  Xout[(size_t)bt * D_ + d] = acc;
  XoutH[(size_t)bt * D_ + d] = (_Float16)acc;
}

// ---------------------------------------------------------------------------
// MFMA self-attention, fp16 qkv input, fp16 output (structure proven in r5).
// ---------------------------------------------------------------------------
#define RS_ 72
__global__ __launch_bounds__(256) void self_attn(
    const _Float16* __restrict__ QKV, _Float16* __restrict__ O) {
  __shared__ _Float16 Ks[64 * RS_];
  __shared__ _Float16 VTs[64 * RS_];
  __shared__ _Float16 Ps[4][16 * RS_];
  const int qt = blockIdx.x, h = blockIdx.y, b = blockIdx.z;
  const int tid = threadIdx.x;
  const int wave = tid >> 6, lane = tid & 63;
  const int lo = lane & 15, hi = lane >> 4;
  const float slope = exp2f(-2.f * (float)(h + 1));
  const int qloc = wave * 16 + lo;
  const int tq = qt * 64 + qloc;
  const size_t base = (size_t)b * T_ * 768 + h * 64;

  half8 qf[2];
#pragma unroll
  for (int s = 0; s < 2; ++s)
    qf[s] = *reinterpret_cast<const half8*>(
        QKV + base + (size_t)(qt * 64 + qloc) * 768 + s * 32 + hi * 8);

  f32x4 oacc[4] = {};
  float mrun = -1e30f, lrun = 0.f;

  for (int kt = 0; kt <= qt; ++kt) {
    __syncthreads();
    for (int c = tid; c < 512; c += 256) {
      const int j = c >> 3, ch = c & 7;
      const size_t rowoff = base + (size_t)(kt * 64 + j) * 768;
      *reinterpret_cast<half8*>(&Ks[j * RS_ + ch * 8]) =
          *reinterpret_cast<const half8*>(QKV + rowoff + 256 + ch * 8);
      const half8 vv = *reinterpret_cast<const half8*>(QKV + rowoff + 512 + ch * 8);
#pragma unroll
      for (int r = 0; r < 8; ++r) {
        const int d = ch * 8 + r;
        const int sw = ((d & 7) ^ (d >> 3)) << 3;
        VTs[d * RS_ + (j ^ sw)] = vv[r];
      }
    }
    __syncthreads();

    f32x4 st[4] = {};
#pragma unroll
    for (int f = 0; f < 4; ++f) {
#pragma unroll
      for (int s = 0; s < 2; ++s) {
        const half8 kf = *reinterpret_cast<const half8*>(
            &Ks[(f * 16 + lo) * RS_ + s * 32 + hi * 8]);
        st[f] = __builtin_amdgcn_mfma_f32_16x16x32_f16(kf, qf[s], st[f], 0, 0, 0);
      }
    }

    float sc[4][4];
    float tmax = -1e30f;
#pragma unroll
    for (int f = 0; f < 4; ++f)
#pragma unroll
      for (int r = 0; r < 4; ++r) {
        const int j = kt * 64 + f * 16 + hi * 4 + r;
        const int rel = tq - j;
        const float v = (rel >= 0)
            ? st[f][r] * 0.125f - slope * (float)(rel / PERIOD_) : -1e30f;
        sc[f][r] = v;
        tmax = fmaxf(tmax, v);
      }
    tmax = fmaxf(tmax, __shfl_xor(tmax, 16, 64));
    tmax = fmaxf(tmax, __shfl_xor(tmax, 32, 64));
    const float mnew = fmaxf(mrun, tmax);
    const float scale = __expf(mrun - mnew);

    float psum = 0.f;
#pragma unroll
    for (int f = 0; f < 4; ++f) {
      half4 ph;
#pragma unroll
      for (int r = 0; r < 4; ++r) {
        const float pv = __expf(sc[f][r] - mnew);
        psum += pv;
        ph[r] = (_Float16)pv;
      }
      *reinterpret_cast<half4*>(&Ps[wave][lo * RS_ + f * 16 + hi * 4]) = ph;
    }
    psum += __shfl_xor(psum, 16, 64);
    psum += __shfl_xor(psum, 32, 64);
    lrun = lrun * scale + psum;
    mrun = mnew;

    float rsc[4];
#pragma unroll
    for (int r = 0; r < 4; ++r) rsc[r] = __shfl(scale, hi * 4 + r, 64);
#pragma unroll
    for (int nf = 0; nf < 4; ++nf)
#pragma unroll
      for (int r = 0; r < 4; ++r) oacc[nf][r] *= rsc[r];

#pragma unroll
    for (int s = 0; s < 2; ++s) {
      const half8 pf = *reinterpret_cast<const half8*>(
          &Ps[wave][lo * RS_ + s * 32 + hi * 8]);
#pragma unroll
      for (int nf = 0; nf < 4; ++nf) {
        const int d = nf * 16 + lo;
        const int sw = ((d & 7) ^ (d >> 3)) << 3;
        const half8 vf = *reinterpret_cast<const half8*>(
            &VTs[d * RS_ + ((s * 32 + hi * 8) ^ sw)]);
        oacc[nf] = __builtin_amdgcn_mfma_f32_16x16x32_f16(pf, vf, oacc[nf], 0, 0, 0);
      }
    }
  }

  float invl[4];
#pragma unroll
  for (int r = 0; r < 4; ++r) invl[r] = 1.f / __shfl(lrun, hi * 4 + r, 64);
#pragma unroll
  for (int nf = 0; nf < 4; ++nf)
#pragma unroll
    for (int r = 0; r < 4; ++r) {
      const int q = qt * 64 + wave * 16 + hi * 4 + r;
      O[((size_t)b * T_ + q) * D_ + h * 64 + nf * 16 + lo] =
          (_Float16)(oacc[nf][r] * invl[r]);
    }
}

// ---------------------------------------------------------------------------
// Banded cross-attention, fp16 q/kv inputs, fp16 output.
// ---------------------------------------------------------------------------
__global__ __launch_bounds__(256) void cross_attn(
    const _Float16* __restrict__ Q, const _Float16* __restrict__ KV,
    _Float16* __restrict__ O) {
  const int gid = blockIdx.x * 256 + threadIdx.x;
  const int h = gid & 3;
  const int bt = gid >> 2;
  const int t = bt & (T_ - 1);
  const int b = bt >> 10;

  float q[64];
  const _Float16* qp = Q + (size_t)bt * D_ + h * 64;
#pragma unroll
  for (int d0 = 0; d0 < 64; d0 += 8) {
    const half8 v = *reinterpret_cast<const half8*>(qp + d0);
#pragma unroll
    for (int e = 0; e < 8; ++e) q[d0 + e] = (float)v[e];
  }

  const int j0 = (t - WIN_ > 0) ? t - WIN_ : 0;
  const int j1 = (t + WIN_ < S_ - 1) ? t + WIN_ : S_ - 1;
  const int nj = j1 - j0 + 1;

  float sc[9];
  float mx = -1e30f;
#pragma unroll
  for (int jj = 0; jj < 9; ++jj) {
    if (jj < nj) {
      const _Float16* kp = KV + ((size_t)b * S_ + j0 + jj) * 512 + h * 64;
      float s = 0.f;
#pragma unroll
      for (int d0 = 0; d0 < 64; d0 += 8) {
        const half8 kv = *reinterpret_cast<const half8*>(kp + d0);
#pragma unroll
        for (int e = 0; e < 8; ++e) s += q[d0 + e] * (float)kv[e];
      }
      sc[jj] = s * 0.125f;
      mx = fmaxf(mx, sc[jj]);
    } else {
      sc[jj] = -1e30f;
    }
  }
  float l = 0.f;
  float p[9];
#pragma unroll
  for (int jj = 0; jj < 9; ++jj) { p[jj] = __expf(sc[jj] - mx); l += p[jj]; }
  const float inv = 1.f / l;

  float o[64];
#pragma unroll
  for (int d = 0; d < 64; ++d) o[d] = 0.f;
#pragma unroll
  for (int jj = 0; jj < 9; ++jj) {
    if (jj < nj) {
      const float pj = p[jj] * inv;
      const _Float16* vp = KV + ((size_t)b * S_ + j0 + jj) * 512 + 256 + h * 64;
#pragma unroll
      for (int d0 = 0; d0 < 64; d0 += 8) {
        const half8 vv = *reinterpret_cast<const half8*>(vp + d0);
#pragma unroll
        for (int e = 0; e < 8; ++e) o[d0 + e] += pj * (float)vv[e];
      }
    }
  }
  _Float16* op = O + (size_t)bt * D_ + h * 64;
#pragma unroll
  for (int d = 0; d < 64; ++d) op[d] = (_Float16)o[d];
}

// ---------------------------------------------------------------------------
// Out = LayerNorm(X + R) * g + b; writes fp32 + fp16 mirror. Out may == X.
// ---------------------------------------------------------------------------
__global__ __launch_bounds__(256) void ln_res(
    const float* X, const float* __restrict__ R,
    const float* __restrict__ g, const float* __restrict__ bta,
    float* Out, _Float16* __restrict__ OutH) {
  const int wid = threadIdx.x >> 6, lane = threadIdx.x & 63;
  const size_t row = (size_t)blockIdx.x * 4 + wid;
  const float* xp = X + row * D_;
  const float* rp = R + row * D_;
  float v[4];
  float s = 0.f;
#pragma unroll
  for (int k = 0; k < 4; ++k) {
    const int d = lane + k * 64;
    v[k] = xp[d] + rp[d];
    s += v[k];
  }
#pragma unroll
  for (int off = 32; off; off >>= 1) s += __shfl_xor(s, off, 64);
  const float mu = s * (1.f / 256.f);
  float var = 0.f;
#pragma unroll
  for (int k = 0; k < 4; ++k) { const float d = v[k] - mu; var += d * d; }
#pragma unroll
  for (int off = 32; off; off >>= 1) var += __shfl_xor(var, off, 64);
  const float rs = rsqrtf(var * (1.f / 256.f) + 1e-5f);
#pragma unroll
  for (int k = 0; k < 4; ++k) {
    const int d = lane + k * 64;
    const float o = (v[k] - mu) * rs * g[d] + bta[d];
    Out[row * D_ + d] = o;
    OutH[row * D_ + d] = (_Float16)o;
  }
}

// ---------------------------------------------------------------------------
// out = clip(x @ W_vr.T + b_vr, 0, 1).
// ---------------------------------------------------------------------------
__global__ __launch_bounds__(256) void head_clip(
    const float* __restrict__ X, const float* __restrict__ Wv,
    const float* __restrict__ bv, float* __restrict__ Out) {
  const int gid = blockIdx.x * 256 + threadIdx.x;
  if (gid >= M_ * MOTION_) return;
  const int j = gid % MOTION_;
  const int row = gid / MOTION_;
  const float4* xr = reinterpret_cast<const float4*>(X + (size_t)row * D_);
  const float4* wr = reinterpret_cast<const float4*>(Wv + (size_t)j * D_);
  float acc = bv[j];
#pragma unroll
  for (int i = 0; i < 64; ++i) {
    const float4 a = xr[i], w = wr[i];
    acc += a.x * w.x + a.y * w.y + a.z * w.z + a.w * w.w;
  }
  Out[gid] = fminf(fmaxf(acc, 0.f), 1.f);
}

// ---------------------------------------------------------------------------
extern "C" void kernel_launch(void* const* d_in, const int* in_sizes, int n_in,
                              void* d_out, int out_size, void* d_ws, size_t ws_size,
                              hipStream_t stream) {
  (void)in_sizes; (void)n_in; (void)out_size; (void)ws_size;
  const float* hidden = (const float*)d_in[0];
  const float* tmot   = (const float*)d_in[1];
  const float* W_af   = (const float*)d_in[2];
  const float* b_af   = (const float*)d_in[3];
  const float* c1w    = (const float*)d_in[4];
  const float* c1b    = (const float*)d_in[5];
  const float* c2w    = (const float*)d_in[6];
  const float* c2b    = (const float*)d_in[7];
  const float* Wvm    = (const float*)d_in[8];
  const float* bvm    = (const float*)d_in[9];
  const float* sa_in_w  = (const float*)d_in[10];
  const float* sa_in_b  = (const float*)d_in[11];
  const float* sa_out_w = (const float*)d_in[12];
  const float* sa_out_b = (const float*)d_in[13];
  const float* ca_in_w  = (const float*)d_in[14];
  const float* ca_in_b  = (const float*)d_in[15];
  const float* ca_out_w = (const float*)d_in[16];
  const float* ca_out_b = (const float*)d_in[17];
  const float* ln1g = (const float*)d_in[18];
  const float* ln1b = (const float*)d_in[19];
  const float* ln2g = (const float*)d_in[20];
  const float* ln2b = (const float*)d_in[21];
  const float* ln3g = (const float*)d_in[22];
  const float* ln3b = (const float*)d_in[23];
  const float* ff1w = (const float*)d_in[24];
  const float* ff1b = (const float*)d_in[25];
  const float* ff2w = (const float*)d_in[26];
  const float* ff2b = (const float*)d_in[27];
  const float* Wvr  = (const float*)d_in[28];
  const float* bvr  = (const float*)d_in[29];
  float* out = (float*)d_out;

  float* ws = (float*)d_ws;
  const size_t BSD = (size_t)M_ * D_;  // 2,097,152
  float* audio = ws;                    // [0,1) BSD  fp32
  float* x     = ws + BSD;              // [1,2) fp32
  float* t1    = ws + 2 * BSD;          // [2,3) fp32
  _Float16* hb = (_Float16*)(ws + 3 * BSD);
  _Float16* Rh      = hb;               // 3*BSD halves, time-shared:
                                        //  hidden_h | t1_h | qkv_h | cq_h+ckv_h | h_h
  _Float16* x_h     = hb + 3 * BSD;
  _Float16* audio_h = hb + 4 * BSD;
  _Float16* att_h   = hb + 5 * BSD;
  _Float16* wH      = hb + 6 * BSD;     // WH_TOT halves
  _Float16* ckv_h   = Rh + BSD;

  const dim3 blk(256);

  // one-shot fp16 conversion: weights (+conv repack) and hidden_states
  CvtSrc cs;
  cs.p[0] = W_af;
  cs.p[1] = sa_in_w;            cs.p[2] = sa_in_w + 768 * 256;
  cs.p[3] = sa_out_w;           cs.p[4] = sa_out_w + 256 * 256;
  cs.p[5] = ca_in_w;            cs.p[6] = ca_in_w + 768 * 256;
  cs.p[7] = ca_out_w;           cs.p[8] = ca_out_w + 256 * 256;
  cs.p[9] = ff1w;               cs.p[10] = ff1w + 512 * 256;
  cs.p[11] = ff2w;              cs.p[12] = ff2w + 256 * 512;
  cs.p[13] = c1w;               cs.p[14] = c2w;
  cs.p[15] = hidden;
  cvt_all<<<dim3((WH_TOT + HID_TOT + 255) / 256), blk, 0, stream>>>(cs, wH, Rh);

  // audio front-end: linear (fp32 out for conv2 residual + fp16 mirror), convs
  gemm_h<<<dim3(M_ / 64, 4), blk, 0, stream>>>(Rh, wH + O_AF, b_af, audio, audio_h,
                                               M_, 256, 768, 0);
  conv_h<<<dim3(128, 4), blk, 0, stream>>>(audio_h, wH + O_CONV1, c1b, Rh, nullptr, 0);
  conv_h<<<dim3(128, 4), blk, 0, stream>>>(Rh, wH + O_CONV2, c2b, audio_h, audio, 1);

  // motion embedding + PE
  motion_pe<<<dim3(M_), blk, 0, stream>>>(tmot, Wvm, bvm, x, x_h);

  for (int l = 0; l < 2; ++l) {
    // self-attention
    gemm_h<<<dim3(M_ / 64, 12), blk, 0, stream>>>(
        x_h, wH + O_SAIN + l * 196608, sa_in_b + l * 768, nullptr, Rh, M_, 768, 256, 0);
    self_attn<<<dim3(T_ / 64, H_, B_), blk, 0, stream>>>(Rh, att_h);
    gemm_h<<<dim3(M_ / 64, 4), blk, 0, stream>>>(
        att_h, wH + O_SAOUT + l * 65536, sa_out_b + l * 256, t1, nullptr, M_, 256, 256, 0);
    ln_res<<<dim3(M_ / 4), blk, 0, stream>>>(x, t1, ln1g + l * 256, ln1b + l * 256, x, x_h);

    // cross-attention (banded)
    gemm_h<<<dim3(M_ / 64, 4), blk, 0, stream>>>(
        x_h, wH + O_CAIN + l * 196608, ca_in_b + l * 768, nullptr, Rh, M_, 256, 256, 0);
    gemm_h<<<dim3(M_ / 64, 8), blk, 0, stream>>>(
        audio_h, wH + O_CAIN + l * 196608 + 65536, ca_in_b + l * 768 + 256,
        nullptr, ckv_h, M_, 512, 256, 0);
    cross_attn<<<dim3(M_ * H_ / 256), blk, 0, stream>>>(Rh, ckv_h, att_h);
    gemm_h<<<dim3(M_ / 64, 4), blk, 0, stream>>>(
        att_h, wH + O_CAOUT + l * 65536, ca_out_b + l * 256, t1, nullptr, M_, 256, 256, 0);
    ln_res<<<dim3(M_ / 4), blk, 0, stream>>>(x, t1, ln2g + l * 256, ln2b + l * 256, x, x_h);

    // FFN
    gemm_h<<<dim3(M_ / 64, 8), blk, 0, stream>>>(
        x_h, wH + O_FF1 + l * 131072, ff1b + l * 512, nullptr, Rh, M_, 512, 256, 1);
    gemm_h<<<dim3(M_ / 64, 4), blk, 0, stream>>>(
        Rh, wH + O_FF2 + l * 131072, ff2b + l * 256, t1, nullptr, M_, 256, 512, 0);
    ln_res<<<dim3(M_ / 4), blk, 0, stream>>>(x, t1, ln3g + l * 256, ln3b + l * 256, x, x_h);
  }

  head_clip<<<dim3((M_ * MOTION_ + 255) / 256), blk, 0, stream>>>(x, Wvr, bvr, out);
}

// Round 8
// 372.099 us; speedup vs baseline: 1.7134x; 1.1452x over previous
//
#include <hip/hip_runtime.h>
#include <math.h>

#define B_ 8
#define T_ 1024
#define S_ 1024
#define D_ 256
#define H_ 4
#define DH_ 64
#define AUDIO_ 768
#define MOTION_ 33
#define PERIOD_ 30
#define WIN_ 4
#define M_ (B_ * T_)

typedef _Float16 half8 __attribute__((ext_vector_type(8)));
typedef _Float16 half4 __attribute__((ext_vector_type(4)));
typedef __attribute__((ext_vector_type(4))) float f32x4;

// fp16 weight arena offsets (halves)
#define O_AF    0
#define O_SAIN  196608   // + l*196608
#define O_SAOUT 589824   // + l*65536
#define O_CAIN  720896   // + l*196608
#define O_CAOUT 1114112  // + l*65536
#define O_FF1   1245184  // + l*131072
#define O_FF2   1507328  // + l*131072
#define O_CONV1 1769472
#define O_CONV2 2097152
#define O_VR    2424832  // W_vr padded to 64x256
#define WH_TOT  2441216
#define HID_TOT 6291456  // 8192*768

struct CvtSrc { const float* p[17]; };

// ---------------------------------------------------------------------------
// One-shot fp32->fp16 conversion of all weights (+ conv repack to
// [oc][tap*256+cin], + W_vr zero-padded to 64 rows) and hidden_states.
// ---------------------------------------------------------------------------
__global__ __launch_bounds__(256) void cvt_all(
    CvtSrc s, _Float16* __restrict__ wH, _Float16* __restrict__ hidH) {
  const long i = (long)blockIdx.x * 256 + threadIdx.x;
  if (i >= (long)WH_TOT + HID_TOT) return;
  if (i >= WH_TOT) { const long j = i - WH_TOT; hidH[j] = (_Float16)s.p[15][j]; return; }
  if (i >= O_VR) {
    const long j = i - O_VR, oc = j >> 8, cin = j & 255;
    wH[i] = (oc < MOTION_) ? (_Float16)s.p[16][oc * 256 + cin] : (_Float16)0.f;
    return;
  }
  if (i >= O_CONV2) {
    const long j = i - O_CONV2, oc = j / 1280, r = j % 1280, tap = r >> 8, cin = r & 255;
    wH[i] = (_Float16)s.p[14][(oc * 256 + cin) * 5 + tap]; return;
  }
  if (i >= O_CONV1) {
    const long j = i - O_CONV1, oc = j / 1280, r = j % 1280, tap = r >> 8, cin = r & 255;
    wH[i] = (_Float16)s.p[13][(oc * 256 + cin) * 5 + tap]; return;
  }
  int seg; long base;
  if      (i >= 1638400) { seg = 12; base = 1638400; }
  else if (i >= 1507328) { seg = 11; base = 1507328; }
  else if (i >= 1376256) { seg = 10; base = 1376256; }
  else if (i >= 1245184) { seg = 9;  base = 1245184; }
  else if (i >= 1179648) { seg = 8;  base = 1179648; }
  else if (i >= 1114112) { seg = 7;  base = 1114112; }
  else if (i >= 917504)  { seg = 6;  base = 917504; }
  else if (i >= 720896)  { seg = 5;  base = 720896; }
  else if (i >= 655360)  { seg = 4;  base = 655360; }
  else if (i >= 589824)  { seg = 3;  base = 589824; }
  else if (i >= 393216)  { seg = 2;  base = 393216; }
  else if (i >= 196608)  { seg = 1;  base = 196608; }
  else                   { seg = 0;  base = 0; }
  wH[i] = (_Float16)s.p[seg][i - base];
}

// ---------------------------------------------------------------------------
// fp16 GEMM: C = A @ W.T + bias. Tile 64x64, BK=64 (8 MFMA per wave per
// barrier pair), register prefetch of next K-chunk. K % 64 == 0.
// Outputs: Cf (fp32, nullable), Ch (fp16 mirror, nullable), optional relu.
// ---------------------------------------------------------------------------
__global__ __launch_bounds__(256) void gemm_h(
    const _Float16* __restrict__ A, const _Float16* __restrict__ W,
    const float* __restrict__ bias, float* __restrict__ Cf,
    _Float16* __restrict__ Ch, int M, int N, int K, int relu) {
  __shared__ _Float16 As[64][72];  // 72 = 64 + 8 pad (144 B row stride)
  __shared__ _Float16 Bs[64][72];
  const int tid = threadIdx.x;
  const int wave = tid >> 6, lane = tid & 63;
  const int wr = wave >> 1, wc = wave & 1;
  const int lr16 = lane & 15, kq = lane >> 4;
  const int bm = blockIdx.x, bn = blockIdx.y;
  const int sr = tid >> 2, sq = tid & 3;

  const _Float16* Ap = A + (size_t)(bm * 64 + sr) * K + sq * 8;
  const _Float16* Wp = W + (size_t)(bn * 64 + sr) * K + sq * 8;

  half8 ra0 = *reinterpret_cast<const half8*>(Ap);
  half8 ra1 = *reinterpret_cast<const half8*>(Ap + 32);
  half8 rw0 = *reinterpret_cast<const half8*>(Wp);
  half8 rw1 = *reinterpret_cast<const half8*>(Wp + 32);
  f32x4 acc[2][2] = {};

  for (int k0 = 0; k0 < K; k0 += 64) {
    __syncthreads();
    *reinterpret_cast<half8*>(&As[sr][sq * 8]) = ra0;
    *reinterpret_cast<half8*>(&As[sr][32 + sq * 8]) = ra1;
    *reinterpret_cast<half8*>(&Bs[sr][sq * 8]) = rw0;
    *reinterpret_cast<half8*>(&Bs[sr][32 + sq * 8]) = rw1;
    __syncthreads();
    if (k0 + 64 < K) {
      ra0 = *reinterpret_cast<const half8*>(Ap + k0 + 64);
      ra1 = *reinterpret_cast<const half8*>(Ap + k0 + 96);
      rw0 = *reinterpret_cast<const half8*>(Wp + k0 + 64);
      rw1 = *reinterpret_cast<const half8*>(Wp + k0 + 96);
    }
    half8 af[2][2], bf[2][2];
#pragma unroll
    for (int m = 0; m < 2; ++m)
#pragma unroll
      for (int s = 0; s < 2; ++s)
        af[m][s] = *reinterpret_cast<const half8*>(
            &As[wr * 32 + m * 16 + lr16][s * 32 + kq * 8]);
#pragma unroll
    for (int n = 0; n < 2; ++n)
#pragma unroll
      for (int s = 0; s < 2; ++s)
        bf[n][s] = *reinterpret_cast<const half8*>(
            &Bs[wc * 32 + n * 16 + lr16][s * 32 + kq * 8]);
#pragma unroll
    for (int m = 0; m < 2; ++m)
#pragma unroll
      for (int n = 0; n < 2; ++n)
#pragma unroll
        for (int s = 0; s < 2; ++s)
          acc[m][n] = __builtin_amdgcn_mfma_f32_16x16x32_f16(af[m][s], bf[n][s], acc[m][n], 0, 0, 0);
  }

#pragma unroll
  for (int m = 0; m < 2; ++m) {
#pragma unroll
    for (int n = 0; n < 2; ++n) {
      const int col = bn * 64 + wc * 32 + n * 16 + lr16;
      const float bv = bias[col];
#pragma unroll
      for (int j = 0; j < 4; ++j) {
        const int row = bm * 64 + wr * 32 + m * 16 + kq * 4 + j;
        float v = acc[m][n][j] + bv;
        if (relu) v = fmaxf(v, 0.f);
        const size_t idx = (size_t)row * N + col;
        if (Cf) Cf[idx] = v;
        if (Ch) Ch[idx] = (_Float16)v;
      }
    }
  }
}

// ---------------------------------------------------------------------------
// Conv1d k=5 as fp16 GEMM, K=1280 tap-major repacked weights, BK=64
// (chunks never cross tap boundaries since 256 % 64 == 0).
// mode 0: OutH = fp16(gelu(v));  mode 1: OutH = fp16(v + ResF).
// ---------------------------------------------------------------------------
__device__ __forceinline__ half8 conv_ld(const _Float16* Xb, int p, int tap, int cin) {
  const int sp = p + tap - 2;
  if (sp < 0 || sp >= S_) { half8 z = {}; return z; }
  return *reinterpret_cast<const half8*>(Xb + (size_t)sp * D_ + cin);
}

__global__ __launch_bounds__(256) void conv_h(
    const _Float16* __restrict__ Xh, const _Float16* __restrict__ Wc,
    const float* __restrict__ bias, _Float16* __restrict__ OutH,
    const float* __restrict__ ResF, int mode) {
  __shared__ _Float16 As[64][72];
  __shared__ _Float16 Bs[64][72];
  const int tid = threadIdx.x;
  const int wave = tid >> 6, lane = tid & 63;
  const int wr = wave >> 1, wc = wave & 1;
  const int lr16 = lane & 15, kq = lane >> 4;
  const int b = blockIdx.x >> 4;
  const int s0 = (blockIdx.x & 15) * 64;
  const int o0 = blockIdx.y * 64;
  const int sr = tid >> 2, sq = tid & 3;

  const _Float16* Xb = Xh + (size_t)b * S_ * D_;
  const _Float16* Wp = Wc + (size_t)(o0 + sr) * 1280 + sq * 8;
  const int p = s0 + sr;

  half8 ra0 = conv_ld(Xb, p, 0, sq * 8);
  half8 ra1 = conv_ld(Xb, p, 0, 32 + sq * 8);
  half8 rw0 = *reinterpret_cast<const half8*>(Wp);
  half8 rw1 = *reinterpret_cast<const half8*>(Wp + 32);
  f32x4 acc[2][2] = {};

  for (int k0 = 0; k0 < 1280; k0 += 64) {
    __syncthreads();
    *reinterpret_cast<half8*>(&As[sr][sq * 8]) = ra0;
    *reinterpret_cast<half8*>(&As[sr][32 + sq * 8]) = ra1;
    *reinterpret_cast<half8*>(&Bs[sr][sq * 8]) = rw0;
    *reinterpret_cast<half8*>(&Bs[sr][32 + sq * 8]) = rw1;
    __syncthreads();
    if (k0 + 64 < 1280) {
      const int kn = k0 + 64;
      const int tap = kn >> 8, cb = kn & 255;
      ra0 = conv_ld(Xb, p, tap, cb + sq * 8);
      ra1 = conv_ld(Xb, p, tap, cb + 32 + sq * 8);
      rw0 = *reinterpret_cast<const half8*>(Wp + kn);
      rw1 = *reinterpret_cast<const half8*>(Wp + kn + 32);
    }
    half8 af[2][2], bf[2][2];
#pragma unroll
    for (int m = 0; m < 2; ++m)
#pragma unroll
      for (int s = 0; s < 2; ++s)
        af[m][s] = *reinterpret_cast<const half8*>(
            &As[wr * 32 + m * 16 + lr16][s * 32 + kq * 8]);
#pragma unroll
    for (int n = 0; n < 2; ++n)
#pragma unroll
      for (int s = 0; s < 2; ++s)
        bf[n][s] = *reinterpret_cast<const half8*>(
            &Bs[wc * 32 + n * 16 + lr16][s * 32 + kq * 8]);
#pragma unroll
    for (int m = 0; m < 2; ++m)
#pragma unroll
      for (int n = 0; n < 2; ++n)
#pragma unroll
        for (int s = 0; s < 2; ++s)
          acc[m][n] = __builtin_amdgcn_mfma_f32_16x16x32_f16(af[m][s], bf[n][s], acc[m][n], 0, 0, 0);
  }

#pragma unroll
  for (int m = 0; m < 2; ++m) {
#pragma unroll
    for (int n = 0; n < 2; ++n) {
      const int oc = o0 + wc * 32 + n * 16 + lr16;
      const float bv = bias[oc];
#pragma unroll
      for (int j = 0; j < 4; ++j) {
        const int s = s0 + wr * 32 + m * 16 + kq * 4 + j;
        const size_t idx = ((size_t)b * S_ + s) * D_ + oc;
        float v = acc[m][n][j] + bv;
        if (mode == 0) {
          v = 0.5f * v * (1.f + erff(v * 0.70710678118654752f));
        } else {
          v += ResF[idx];
        }
        OutH[idx] = (_Float16)v;
      }
    }
  }
}

// ---------------------------------------------------------------------------
// Head: out = clip(x @ W_vr.T + b_vr, 0, 1) via MFMA (W_vr padded to 64 rows).
// Same 64x64/BK=64 structure; epilogue writes packed [M,33] with clip.
// ---------------------------------------------------------------------------
__global__ __launch_bounds__(256) void head_mfma(
    const _Float16* __restrict__ Xh, const _Float16* __restrict__ Wh,
    const float* __restrict__ bv, float* __restrict__ Out) {
  __shared__ _Float16 As[64][72];
  __shared__ _Float16 Bs[64][72];
  const int tid = threadIdx.x;
  const int wave = tid >> 6, lane = tid & 63;
  const int wr = wave >> 1, wc = wave & 1;
  const int lr16 = lane & 15, kq = lane >> 4;
  const int bm = blockIdx.x;
  const int sr = tid >> 2, sq = tid & 3;

  const _Float16* Ap = Xh + (size_t)(bm * 64 + sr) * D_ + sq * 8;
  const _Float16* Wp = Wh + (size_t)sr * D_ + sq * 8;

  half8 ra0 = *reinterpret_cast<const half8*>(Ap);
  half8 ra1 = *reinterpret_cast<const half8*>(Ap + 32);
  half8 rw0 = *reinterpret_cast<const half8*>(Wp);
  half8 rw1 = *reinterpret_cast<const half8*>(Wp + 32);
  f32x4 acc[2][2] = {};

  for (int k0 = 0; k0 < D_; k0 += 64) {
    __syncthreads();
    *reinterpret_cast<half8*>(&As[sr][sq * 8]) = ra0;
    *reinterpret_cast<half8*>(&As[sr][32 + sq * 8]) = ra1;
    *reinterpret_cast<half8*>(&Bs[sr][sq * 8]) = rw0;
    *reinterpret_cast<half8*>(&Bs[sr][32 + sq * 8]) = rw1;
    __syncthreads();
    if (k0 + 64 < D_) {
      ra0 = *reinterpret_cast<const half8*>(Ap + k0 + 64);
      ra1 = *reinterpret_cast<const half8*>(Ap + k0 + 96);
      rw0 = *reinterpret_cast<const half8*>(Wp + k0 + 64);
      rw1 = *reinterpret_cast<const half8*>(Wp + k0 + 96);
    }
    half8 af[2][2], bf[2][2];
#pragma unroll
    for (int m = 0; m < 2; ++m)
#pragma unroll
      for (int s = 0; s < 2; ++s)
        af[m][s] = *reinterpret_cast<const half8*>(
            &As[wr * 32 + m * 16 + lr16][s * 32 + kq * 8]);
#pragma unroll
    for (int n = 0; n < 2; ++n)
#pragma unroll
      for (int s = 0; s < 2; ++s)
        bf[n][s] = *reinterpret_cast<const half8*>(
            &Bs[wc * 32 + n * 16 + lr16][s * 32 + kq * 8]);
#pragma unroll
    for (int m = 0; m < 2; ++m)
#pragma unroll
      for (int n = 0; n < 2; ++n)
#pragma unroll
        for (int s = 0; s < 2; ++s)
          acc[m][n] = __builtin_amdgcn_mfma_f32_16x16x32_f16(af[m][s], bf[n][s], acc[m][n], 0, 0, 0);
  }

#pragma unroll
  for (int m = 0; m < 2; ++m) {
#pragma unroll
    for (int n = 0; n < 2; ++n) {
      const int col = wc * 32 + n * 16 + lr16;
      if (col < MOTION_) {
        const float bb = bv[col];
#pragma unroll
        for (int j = 0; j < 4; ++j) {
          const int row = bm * 64 + wr * 32 + m * 16 + kq * 4 + j;
          float v = acc[m][n][j] + bb;
          Out[(size_t)row * MOTION_ + col] = fminf(fmaxf(v, 0.f), 1.f);
        }
      }
    }
  }
}

// ---------------------------------------------------------------------------
// x = shifted_motion @ W_vm.T + b_vm + PE(t%30); writes fp32 + fp16 mirror.
// ---------------------------------------------------------------------------
__global__ __launch_bounds__(256) void motion_pe(
    const float* __restrict__ TM, const float* __restrict__ Wvm,
    const float* __restrict__ bvm, float* __restrict__ Xout,
    _Float16* __restrict__ XoutH) {
  const int d = threadIdx.x;
  const int bt = blockIdx.x;
  const int t = bt & (T_ - 1);
  const int b = bt >> 10;
  float acc = bvm[d];
  if (t > 0) {
    const float* mrow = TM + ((size_t)b * T_ + t - 1) * MOTION_;
    const float* wrow = Wvm + (size_t)d * MOTION_;
#pragma unroll
    for (int m = 0; m < MOTION_; ++m) acc += mrow[m] * wrow[m];
  }
  const int pos = t % PERIOD_;
  const int i2 = d >> 1;
  const float div = expf((float)(2 * i2) * (-9.210340371976184f / 256.f));
  const float ang = (float)pos * div;
  acc += (d & 1) ? cosf(ang) : sinf(ang);
  Xout[(size_t)bt * D_ + d] = acc;
  XoutH[(size_t)bt * D_ + d] = (_Float16)acc;
}

// ---------------------------------------------------------------------------
// MFMA self-attention, fp16 qkv input, fp16 output (proven structure).
// ---------------------------------------------------------------------------
#define RS_ 72
__global__ __launch_bounds__(256) void self_attn(
    const _Float16* __restrict__ QKV, _Float16* __restrict__ O) {
  __shared__ _Float16 Ks[64 * RS_];
  __shared__ _Float16 VTs[64 * RS_];
  __shared__ _Float16 Ps[4][16 * RS_];
  const int qt = blockIdx.x, h = blockIdx.y, b = blockIdx.z;
  const int tid = threadIdx.x;
  const int wave = tid >> 6, lane = tid & 63;
  const int lo = lane & 15, hi = lane >> 4;
  const float slope = exp2f(-2.f * (float)(h + 1));
  const int qloc = wave * 16 + lo;
  const int tq = qt * 64 + qloc;
  const size_t base = (size_t)b * T_ * 768 + h * 64;

  half8 qf[2];
#pragma unroll
  for (int s = 0; s < 2; ++s)
    qf[s] = *reinterpret_cast<const half8*>(
        QKV + base + (size_t)(qt * 64 + qloc) * 768 + s * 32 + hi * 8);

  f32x4 oacc[4] = {};
  float mrun = -1e30f, lrun = 0.f;

  for (int kt = 0; kt <= qt; ++kt) {
    __syncthreads();
    for (int c = tid; c < 512; c += 256) {
      const int j = c >> 3, ch = c & 7;
      const size_t rowoff = base + (size_t)(kt * 64 + j) * 768;
      *reinterpret_cast<half8*>(&Ks[j * RS_ + ch * 8]) =
          *reinterpret_cast<const half8*>(QKV + rowoff + 256 + ch * 8);
      const half8 vv = *reinterpret_cast<const half8*>(QKV + rowoff + 512 + ch * 8);
#pragma unroll
      for (int r = 0; r < 8; ++r) {
        const int d = ch * 8 + r;
        const int sw = ((d & 7) ^ (d >> 3)) << 3;
        VTs[d * RS_ + (j ^ sw)] = vv[r];
      }
    }
    __syncthreads();

    f32x4 st[4] = {};
#pragma unroll
    for (int f = 0; f < 4; ++f) {
#pragma unroll
      for (int s = 0; s < 2; ++s) {
        const half8 kf = *reinterpret_cast<const half8*>(
            &Ks[(f * 16 + lo) * RS_ + s * 32 + hi * 8]);
        st[f] = __builtin_amdgcn_mfma_f32_16x16x32_f16(kf, qf[s], st[f], 0, 0, 0);
      }
    }

    float sc[4][4];
    float tmax = -1e30f;
#pragma unroll
    for (int f = 0; f < 4; ++f)
#pragma unroll
      for (int r = 0; r < 4; ++r) {
        const int j = kt * 64 + f * 16 + hi * 4 + r;
        const int rel = tq - j;
        const float v = (rel >= 0)
            ? st[f][r] * 0.125f - slope * (float)(rel / PERIOD_) : -1e30f;
        sc[f][r] = v;
        tmax = fmaxf(tmax, v);
      }
    tmax = fmaxf(tmax, __shfl_xor(tmax, 16, 64));
    tmax = fmaxf(tmax, __shfl_xor(tmax, 32, 64));
    const float mnew = fmaxf(mrun, tmax);
    const float scale = __expf(mrun - mnew);

    float psum = 0.f;
#pragma unroll
    for (int f = 0; f < 4; ++f) {
      half4 ph;
#pragma unroll
      for (int r = 0; r < 4; ++r) {
        const float pv = __expf(sc[f][r] - mnew);
        psum += pv;
        ph[r] = (_Float16)pv;
      }
      *reinterpret_cast<half4*>(&Ps[wave][lo * RS_ + f * 16 + hi * 4]) = ph;
    }
    psum += __shfl_xor(psum, 16, 64);
    psum += __shfl_xor(psum, 32, 64);
    lrun = lrun * scale + psum;
    mrun = mnew;

    float rsc[4];
#pragma unroll
    for (int r = 0; r < 4; ++r) rsc[r] = __shfl(scale, hi * 4 + r, 64);
#pragma unroll
    for (int nf = 0; nf < 4; ++nf)
#pragma unroll
      for (int r = 0; r < 4; ++r) oacc[nf][r] *= rsc[r];

#pragma unroll
    for (int s = 0; s < 2; ++s) {
      const half8 pf = *reinterpret_cast<const half8*>(
          &Ps[wave][lo * RS_ + s * 32 + hi * 8]);
#pragma unroll
      for (int nf = 0; nf < 4; ++nf) {
        const int d = nf * 16 + lo;
        const int sw = ((d & 7) ^ (d >> 3)) << 3;
        const half8 vf = *reinterpret_cast<const half8*>(
            &VTs[d * RS_ + ((s * 32 + hi * 8) ^ sw)]);
        oacc[nf] = __builtin_amdgcn_mfma_f32_16x16x32_f16(pf, vf, oacc[nf], 0, 0, 0);
      }
    }
  }

  float invl[4];
#pragma unroll
  for (int r = 0; r < 4; ++r) invl[r] = 1.f / __shfl(lrun, hi * 4 + r, 64);
#pragma unroll
  for (int nf = 0; nf < 4; ++nf)
#pragma unroll
    for (int r = 0; r < 4; ++r) {
      const int q = qt * 64 + wave * 16 + hi * 4 + r;
      O[((size_t)b * T_ + q) * D_ + h * 64 + nf * 16 + lo] =
          (_Float16)(oacc[nf][r] * invl[r]);
    }
}

// ---------------------------------------------------------------------------
// Banded cross-attention, fp16 q/kv inputs, fp16 output.
// ---------------------------------------------------------------------------
__global__ __launch_bounds__(256) void cross_attn(
    const _Float16* __restrict__ Q, const _Float16* __restrict__ KV,
    _Float16* __restrict__ O) {
  const int gid = blockIdx.x * 256 + threadIdx.x;
  const int h = gid & 3;
  const int bt = gid >> 2;
  const int t = bt & (T_ - 1);
  const int b = bt >> 10;

  float q[64];
  const _Float16* qp = Q + (size_t)bt * D_ + h * 64;
#pragma unroll
  for (int d0 = 0; d0 < 64; d0 += 8) {
    const half8 v = *reinterpret_cast<const half8*>(qp + d0);
#pragma unroll
    for (int e = 0; e < 8; ++e) q[d0 + e] = (float)v[e];
  }

  const int j0 = (t - WIN_ > 0) ? t - WIN_ : 0;
  const int j1 = (t + WIN_ < S_ - 1) ? t + WIN_ : S_ - 1;
  const int nj = j1 - j0 + 1;

  float sc[9];
  float mx = -1e30f;
#pragma unroll
  for (int jj = 0; jj < 9; ++jj) {
    if (jj < nj) {
      const _Float16* kp = KV + ((size_t)b * S_ + j0 + jj) * 512 + h * 64;
      float s = 0.f;
#pragma unroll
      for (int d0 = 0; d0 < 64; d0 += 8) {
        const half8 kv = *reinterpret_cast<const half8*>(kp + d0);
#pragma unroll
        for (int e = 0; e < 8; ++e) s += q[d0 + e] * (float)kv[e];
      }
      sc[jj] = s * 0.125f;
      mx = fmaxf(mx, sc[jj]);
    } else {
      sc[jj] = -1e30f;
    }
  }
  float l = 0.f;
  float p[9];
#pragma unroll
  for (int jj = 0; jj < 9; ++jj) { p[jj] = __expf(sc[jj] - mx); l += p[jj]; }
  const float inv = 1.f / l;

  float o[64];
#pragma unroll
  for (int d = 0; d < 64; ++d) o[d] = 0.f;
#pragma unroll
  for (int jj = 0; jj < 9; ++jj) {
    if (jj < nj) {
      const float pj = p[jj] * inv;
      const _Float16* vp = KV + ((size_t)b * S_ + j0 + jj) * 512 + 256 + h * 64;
#pragma unroll
      for (int d0 = 0; d0 < 64; d0 += 8) {
        const half8 vv = *reinterpret_cast<const half8*>(vp + d0);
#pragma unroll
        for (int e = 0; e < 8; ++e) o[d0 + e] += pj * (float)vv[e];
      }
    }
  }
  _Float16* op = O + (size_t)bt * D_ + h * 64;
#pragma unroll
  for (int d = 0; d < 64; ++d) op[d] = (_Float16)o[d];
}

// ---------------------------------------------------------------------------
// Out = LayerNorm(X + R) * g + b; writes fp32 + fp16 mirror. Out may == X.
// ---------------------------------------------------------------------------
__global__ __launch_bounds__(256) void ln_res(
    const float* X, const float* __restrict__ R,
    const float* __restrict__ g, const float* __restrict__ bta,
    float* Out, _Float16* __restrict__ OutH) {
  const int wid = threadIdx.x >> 6, lane = threadIdx.x & 63;
  const size_t row = (size_t)blockIdx.x * 4 + wid;
  const float* xp = X + row * D_;
  const float* rp = R + row * D_;
  float v[4];
  float s = 0.f;
#pragma unroll
  for (int k = 0; k < 4; ++k) {
    const int d = lane + k * 64;
    v[k] = xp[d] + rp[d];
    s += v[k];
  }
#pragma unroll
  for (int off = 32; off; off >>= 1) s += __shfl_xor(s, off, 64);
  const float mu = s * (1.f / 256.f);
  float var = 0.f;
#pragma unroll
  for (int k = 0; k < 4; ++k) { const float d = v[k] - mu; var += d * d; }
#pragma unroll
  for (int off = 32; off; off >>= 1) var += __shfl_xor(var, off, 64);
  const float rs = rsqrtf(var * (1.f / 256.f) + 1e-5f);
#pragma unroll
  for (int k = 0; k < 4; ++k) {
    const int d = lane + k * 64;
    const float o = (v[k] - mu) * rs * g[d] + bta[d];
    Out[row * D_ + d] = o;
    OutH[row * D_ + d] = (_Float16)o;
  }
}

// ---------------------------------------------------------------------------
extern "C" void kernel_launch(void* const* d_in, const int* in_sizes, int n_in,
                              void* d_out, int out_size, void* d_ws, size_t ws_size,
                              hipStream_t stream) {
  (void)in_sizes; (void)n_in; (void)out_size; (void)ws_size;
  const float* hidden = (const float*)d_in[0];
  const float* tmot   = (const float*)d_in[1];
  const float* W_af   = (const float*)d_in[2];
  const float* b_af   = (const float*)d_in[3];
  const float* c1w    = (const float*)d_in[4];
  const float* c1b    = (const float*)d_in[5];
  const float* c2w    = (const float*)d_in[6];
  const float* c2b    = (const float*)d_in[7];
  const float* Wvm    = (const float*)d_in[8];
  const float* bvm    = (const float*)d_in[9];
  const float* sa_in_w  = (const float*)d_in[10];
  const float* sa_in_b  = (const float*)d_in[11];
  const float* sa_out_w = (const float*)d_in[12];
  const float* sa_out_b = (const float*)d_in[13];
  const float* ca_in_w  = (const float*)d_in[14];
  const float* ca_in_b  = (const float*)d_in[15];
  const float* ca_out_w = (const float*)d_in[16];
  const float* ca_out_b = (const float*)d_in[17];
  const float* ln1g = (const float*)d_in[18];
  const float* ln1b = (const float*)d_in[19];
  const float* ln2g = (const float*)d_in[20];
  const float* ln2b = (const float*)d_in[21];
  const float* ln3g = (const float*)d_in[22];
  const float* ln3b = (const float*)d_in[23];
  const float* ff1w = (const float*)d_in[24];
  const float* ff1b = (const float*)d_in[25];
  const float* ff2w = (const float*)d_in[26];
  const float* ff2b = (const float*)d_in[27];
  const float* Wvr  = (const float*)d_in[28];
  const float* bvr  = (const float*)d_in[29];
  float* out = (float*)d_out;

  float* ws = (float*)d_ws;
  const size_t BSD = (size_t)M_ * D_;  // 2,097,152
  float* audio = ws;                    // fp32
  float* x     = ws + BSD;              // fp32
  float* t1    = ws + 2 * BSD;          // fp32
  _Float16* hb = (_Float16*)(ws + 3 * BSD);
  _Float16* Rh      = hb;               // 3*BSD halves, time-shared
  _Float16* x_h     = hb + 3 * BSD;
  _Float16* audio_h = hb + 4 * BSD;
  _Float16* att_h   = hb + 5 * BSD;
  _Float16* wH      = hb + 6 * BSD;     // WH_TOT halves
  _Float16* ckv_h   = Rh + BSD;

  const dim3 blk(256);

  // one-shot fp16 conversion: weights (+conv repack, +W_vr pad) and hidden
  CvtSrc cs;
  cs.p[0] = W_af;
  cs.p[1] = sa_in_w;            cs.p[2] = sa_in_w + 768 * 256;
  cs.p[3] = sa_out_w;           cs.p[4] = sa_out_w + 256 * 256;
  cs.p[5] = ca_in_w;            cs.p[6] = ca_in_w + 768 * 256;
  cs.p[7] = ca_out_w;           cs.p[8] = ca_out_w + 256 * 256;
  cs.p[9] = ff1w;               cs.p[10] = ff1w + 512 * 256;
  cs.p[11] = ff2w;              cs.p[12] = ff2w + 256 * 512;
  cs.p[13] = c1w;               cs.p[14] = c2w;
  cs.p[15] = hidden;            cs.p[16] = Wvr;
  cvt_all<<<dim3((WH_TOT + HID_TOT + 255) / 256), blk, 0, stream>>>(cs, wH, Rh);

  // audio front-end
  gemm_h<<<dim3(M_ / 64, 4), blk, 0, stream>>>(Rh, wH + O_AF, b_af, audio, audio_h,
                                               M_, 256, 768, 0);
  conv_h<<<dim3(128, 4), blk, 0, stream>>>(audio_h, wH + O_CONV1, c1b, Rh, nullptr, 0);
  conv_h<<<dim3(128, 4), blk, 0, stream>>>(Rh, wH + O_CONV2, c2b, audio_h, audio, 1);

  // motion embedding + PE
  motion_pe<<<dim3(M_), blk, 0, stream>>>(tmot, Wvm, bvm, x, x_h);

  for (int l = 0; l < 2; ++l) {
    // self-attention
    gemm_h<<<dim3(M_ / 64, 12), blk, 0, stream>>>(
        x_h, wH + O_SAIN + l * 196608, sa_in_b + l * 768, nullptr, Rh, M_, 768, 256, 0);
    self_attn<<<dim3(T_ / 64, H_, B_), blk, 0, stream>>>(Rh, att_h);
    gemm_h<<<dim3(M_ / 64, 4), blk, 0, stream>>>(
        att_h, wH + O_SAOUT + l * 65536, sa_out_b + l * 256, t1, nullptr, M_, 256, 256, 0);
    ln_res<<<dim3(M_ / 4), blk, 0, stream>>>(x, t1, ln1g + l * 256, ln1b + l * 256, x, x_h);

    // cross-attention (banded)
    gemm_h<<<dim3(M_ / 64, 4), blk, 0, stream>>>(
        x_h, wH + O_CAIN + l * 196608, ca_in_b + l * 768, nullptr, Rh, M_, 256, 256, 0);
    gemm_h<<<dim3(M_ / 64, 8), blk, 0, stream>>>(
        audio_h, wH + O_CAIN + l * 196608 + 65536, ca_in_b + l * 768 + 256,
        nullptr, ckv_h, M_, 512, 256, 0);
    cross_attn<<<dim3(M_ * H_ / 256), blk, 0, stream>>>(Rh, ckv_h, att_h);
    gemm_h<<<dim3(M_ / 64, 4), blk, 0, stream>>>(
        att_h, wH + O_CAOUT + l * 65536, ca_out_b + l * 256, t1, nullptr, M_, 256, 256, 0);
    ln_res<<<dim3(M_ / 4), blk, 0, stream>>>(x, t1, ln2g + l * 256, ln2b + l * 256, x, x_h);

    // FFN
    gemm_h<<<dim3(M_ / 64, 8), blk, 0, stream>>>(
        x_h, wH + O_FF1 + l * 131072, ff1b + l * 512, nullptr, Rh, M_, 512, 256, 1);
    gemm_h<<<dim3(M_ / 64, 4), blk, 0, stream>>>(
        Rh, wH + O_FF2 + l * 131072, ff2b + l * 256, t1, nullptr, M_, 256, 512, 0);
    ln_res<<<dim3(M_ / 4), blk, 0, stream>>>(x, t1, ln3g + l * 256, ln3b + l * 256, x, x_h);
  }

  head_mfma<<<dim3(M_ / 64), blk, 0, stream>>>(x_h, wH + O_VR, bvr, out);
}

// Round 9
// 365.914 us; speedup vs baseline: 1.7423x; 1.0169x over previous
//
#include <hip/hip_runtime.h>
#include <math.h>

#define B_ 8
#define T_ 1024
#define S_ 1024
#define D_ 256
#define H_ 4
#define DH_ 64
#define AUDIO_ 768
#define MOTION_ 33
#define PERIOD_ 30
#define WIN_ 4
#define M_ (B_ * T_)

typedef _Float16 half8 __attribute__((ext_vector_type(8)));
typedef _Float16 half4 __attribute__((ext_vector_type(4)));
typedef __attribute__((ext_vector_type(4))) float f32x4;

// fp16 weight arena offsets (halves)
#define O_AF    0
#define O_SAIN  196608   // + l*196608
#define O_SAOUT 589824   // + l*65536
#define O_CAIN  720896   // + l*196608
#define O_CAOUT 1114112  // + l*65536
#define O_FF1   1245184  // + l*131072
#define O_FF2   1507328  // + l*131072
#define O_CONV1 1769472
#define O_CONV2 2097152
#define O_VR    2424832  // W_vr padded to 64x256
#define WH_TOT  2441216
#define HID_TOT 6291456  // 8192*768

struct CvtSrc { const float* p[17]; };

// ---------------------------------------------------------------------------
// One-shot fp32->fp16 conversion of all weights (+ conv repack to
// [oc][tap*256+cin], + W_vr zero-padded to 64 rows) and hidden_states.
// ---------------------------------------------------------------------------
__global__ __launch_bounds__(256) void cvt_all(
    CvtSrc s, _Float16* __restrict__ wH, _Float16* __restrict__ hidH) {
  const long i = (long)blockIdx.x * 256 + threadIdx.x;
  if (i >= (long)WH_TOT + HID_TOT) return;
  if (i >= WH_TOT) { const long j = i - WH_TOT; hidH[j] = (_Float16)s.p[15][j]; return; }
  if (i >= O_VR) {
    const long j = i - O_VR, oc = j >> 8, cin = j & 255;
    wH[i] = (oc < MOTION_) ? (_Float16)s.p[16][oc * 256 + cin] : (_Float16)0.f;
    return;
  }
  if (i >= O_CONV2) {
    const long j = i - O_CONV2, oc = j / 1280, r = j % 1280, tap = r >> 8, cin = r & 255;
    wH[i] = (_Float16)s.p[14][(oc * 256 + cin) * 5 + tap]; return;
  }
  if (i >= O_CONV1) {
    const long j = i - O_CONV1, oc = j / 1280, r = j % 1280, tap = r >> 8, cin = r & 255;
    wH[i] = (_Float16)s.p[13][(oc * 256 + cin) * 5 + tap]; return;
  }
  int seg; long base;
  if      (i >= 1638400) { seg = 12; base = 1638400; }
  else if (i >= 1507328) { seg = 11; base = 1507328; }
  else if (i >= 1376256) { seg = 10; base = 1376256; }
  else if (i >= 1245184) { seg = 9;  base = 1245184; }
  else if (i >= 1179648) { seg = 8;  base = 1179648; }
  else if (i >= 1114112) { seg = 7;  base = 1114112; }
  else if (i >= 917504)  { seg = 6;  base = 917504; }
  else if (i >= 720896)  { seg = 5;  base = 720896; }
  else if (i >= 655360)  { seg = 4;  base = 655360; }
  else if (i >= 589824)  { seg = 3;  base = 589824; }
  else if (i >= 393216)  { seg = 2;  base = 393216; }
  else if (i >= 196608)  { seg = 1;  base = 196608; }
  else                   { seg = 0;  base = 0; }
  wH[i] = (_Float16)s.p[seg][i - base];
}

// ---------------------------------------------------------------------------
// fp16 GEMM: C = A @ W.T + bias. Tile 64x64, BK=64, register prefetch.
// ---------------------------------------------------------------------------
__global__ __launch_bounds__(256) void gemm_h(
    const _Float16* __restrict__ A, const _Float16* __restrict__ W,
    const float* __restrict__ bias, float* __restrict__ Cf,
    _Float16* __restrict__ Ch, int M, int N, int K, int relu) {
  __shared__ _Float16 As[64][72];
  __shared__ _Float16 Bs[64][72];
  const int tid = threadIdx.x;
  const int wave = tid >> 6, lane = tid & 63;
  const int wr = wave >> 1, wc = wave & 1;
  const int lr16 = lane & 15, kq = lane >> 4;
  const int bm = blockIdx.x, bn = blockIdx.y;
  const int sr = tid >> 2, sq = tid & 3;

  const _Float16* Ap = A + (size_t)(bm * 64 + sr) * K + sq * 8;
  const _Float16* Wp = W + (size_t)(bn * 64 + sr) * K + sq * 8;

  half8 ra0 = *reinterpret_cast<const half8*>(Ap);
  half8 ra1 = *reinterpret_cast<const half8*>(Ap + 32);
  half8 rw0 = *reinterpret_cast<const half8*>(Wp);
  half8 rw1 = *reinterpret_cast<const half8*>(Wp + 32);
  f32x4 acc[2][2] = {};

  for (int k0 = 0; k0 < K; k0 += 64) {
    __syncthreads();
    *reinterpret_cast<half8*>(&As[sr][sq * 8]) = ra0;
    *reinterpret_cast<half8*>(&As[sr][32 + sq * 8]) = ra1;
    *reinterpret_cast<half8*>(&Bs[sr][sq * 8]) = rw0;
    *reinterpret_cast<half8*>(&Bs[sr][32 + sq * 8]) = rw1;
    __syncthreads();
    if (k0 + 64 < K) {
      ra0 = *reinterpret_cast<const half8*>(Ap + k0 + 64);
      ra1 = *reinterpret_cast<const half8*>(Ap + k0 + 96);
      rw0 = *reinterpret_cast<const half8*>(Wp + k0 + 64);
      rw1 = *reinterpret_cast<const half8*>(Wp + k0 + 96);
    }
    half8 af[2][2], bf[2][2];
#pragma unroll
    for (int m = 0; m < 2; ++m)
#pragma unroll
      for (int s = 0; s < 2; ++s)
        af[m][s] = *reinterpret_cast<const half8*>(
            &As[wr * 32 + m * 16 + lr16][s * 32 + kq * 8]);
#pragma unroll
    for (int n = 0; n < 2; ++n)
#pragma unroll
      for (int s = 0; s < 2; ++s)
        bf[n][s] = *reinterpret_cast<const half8*>(
            &Bs[wc * 32 + n * 16 + lr16][s * 32 + kq * 8]);
#pragma unroll
    for (int m = 0; m < 2; ++m)
#pragma unroll
      for (int n = 0; n < 2; ++n)
#pragma unroll
        for (int s = 0; s < 2; ++s)
          acc[m][n] = __builtin_amdgcn_mfma_f32_16x16x32_f16(af[m][s], bf[n][s], acc[m][n], 0, 0, 0);
  }

#pragma unroll
  for (int m = 0; m < 2; ++m) {
#pragma unroll
    for (int n = 0; n < 2; ++n) {
      const int col = bn * 64 + wc * 32 + n * 16 + lr16;
      const float bv = bias[col];
#pragma unroll
      for (int j = 0; j < 4; ++j) {
        const int row = bm * 64 + wr * 32 + m * 16 + kq * 4 + j;
        float v = acc[m][n][j] + bv;
        if (relu) v = fmaxf(v, 0.f);
        const size_t idx = (size_t)row * N + col;
        if (Cf) Cf[idx] = v;
        if (Ch) Ch[idx] = (_Float16)v;
      }
    }
  }
}

// ---------------------------------------------------------------------------
// Conv1d k=5 as fp16 GEMM, K=1280 tap-major repacked weights, BK=64.
// ---------------------------------------------------------------------------
__device__ __forceinline__ half8 conv_ld(const _Float16* Xb, int p, int tap, int cin) {
  const int sp = p + tap - 2;
  if (sp < 0 || sp >= S_) { half8 z = {}; return z; }
  return *reinterpret_cast<const half8*>(Xb + (size_t)sp * D_ + cin);
}

__global__ __launch_bounds__(256) void conv_h(
    const _Float16* __restrict__ Xh, const _Float16* __restrict__ Wc,
    const float* __restrict__ bias, _Float16* __restrict__ OutH,
    const float* __restrict__ ResF, int mode) {
  __shared__ _Float16 As[64][72];
  __shared__ _Float16 Bs[64][72];
  const int tid = threadIdx.x;
  const int wave = tid >> 6, lane = tid & 63;
  const int wr = wave >> 1, wc = wave & 1;
  const int lr16 = lane & 15, kq = lane >> 4;
  const int b = blockIdx.x >> 4;
  const int s0 = (blockIdx.x & 15) * 64;
  const int o0 = blockIdx.y * 64;
  const int sr = tid >> 2, sq = tid & 3;

  const _Float16* Xb = Xh + (size_t)b * S_ * D_;
  const _Float16* Wp = Wc + (size_t)(o0 + sr) * 1280 + sq * 8;
  const int p = s0 + sr;

  half8 ra0 = conv_ld(Xb, p, 0, sq * 8);
  half8 ra1 = conv_ld(Xb, p, 0, 32 + sq * 8);
  half8 rw0 = *reinterpret_cast<const half8*>(Wp);
  half8 rw1 = *reinterpret_cast<const half8*>(Wp + 32);
  f32x4 acc[2][2] = {};

  for (int k0 = 0; k0 < 1280; k0 += 64) {
    __syncthreads();
    *reinterpret_cast<half8*>(&As[sr][sq * 8]) = ra0;
    *reinterpret_cast<half8*>(&As[sr][32 + sq * 8]) = ra1;
    *reinterpret_cast<half8*>(&Bs[sr][sq * 8]) = rw0;
    *reinterpret_cast<half8*>(&Bs[sr][32 + sq * 8]) = rw1;
    __syncthreads();
    if (k0 + 64 < 1280) {
      const int kn = k0 + 64;
      const int tap = kn >> 8, cb = kn & 255;
      ra0 = conv_ld(Xb, p, tap, cb + sq * 8);
      ra1 = conv_ld(Xb, p, tap, cb + 32 + sq * 8);
      rw0 = *reinterpret_cast<const half8*>(Wp + kn);
      rw1 = *reinterpret_cast<const half8*>(Wp + kn + 32);
    }
    half8 af[2][2], bf[2][2];
#pragma unroll
    for (int m = 0; m < 2; ++m)
#pragma unroll
      for (int s = 0; s < 2; ++s)
        af[m][s] = *reinterpret_cast<const half8*>(
            &As[wr * 32 + m * 16 + lr16][s * 32 + kq * 8]);
#pragma unroll
    for (int n = 0; n < 2; ++n)
#pragma unroll
      for (int s = 0; s < 2; ++s)
        bf[n][s] = *reinterpret_cast<const half8*>(
            &Bs[wc * 32 + n * 16 + lr16][s * 32 + kq * 8]);
#pragma unroll
    for (int m = 0; m < 2; ++m)
#pragma unroll
      for (int n = 0; n < 2; ++n)
#pragma unroll
        for (int s = 0; s < 2; ++s)
          acc[m][n] = __builtin_amdgcn_mfma_f32_16x16x32_f16(af[m][s], bf[n][s], acc[m][n], 0, 0, 0);
  }

#pragma unroll
  for (int m = 0; m < 2; ++m) {
#pragma unroll
    for (int n = 0; n < 2; ++n) {
      const int oc = o0 + wc * 32 + n * 16 + lr16;
      const float bv = bias[oc];
#pragma unroll
      for (int j = 0; j < 4; ++j) {
        const int s = s0 + wr * 32 + m * 16 + kq * 4 + j;
        const size_t idx = ((size_t)b * S_ + s) * D_ + oc;
        float v = acc[m][n][j] + bv;
        if (mode == 0) {
          v = 0.5f * v * (1.f + erff(v * 0.70710678118654752f));
        } else {
          v += ResF[idx];
        }
        OutH[idx] = (_Float16)v;
      }
    }
  }
}

// ---------------------------------------------------------------------------
// Head: out = clip(x @ W_vr.T + b_vr, 0, 1) via MFMA (W_vr padded to 64).
// ---------------------------------------------------------------------------
__global__ __launch_bounds__(256) void head_mfma(
    const _Float16* __restrict__ Xh, const _Float16* __restrict__ Wh,
    const float* __restrict__ bv, float* __restrict__ Out) {
  __shared__ _Float16 As[64][72];
  __shared__ _Float16 Bs[64][72];
  const int tid = threadIdx.x;
  const int wave = tid >> 6, lane = tid & 63;
  const int wr = wave >> 1, wc = wave & 1;
  const int lr16 = lane & 15, kq = lane >> 4;
  const int bm = blockIdx.x;
  const int sr = tid >> 2, sq = tid & 3;

  const _Float16* Ap = Xh + (size_t)(bm * 64 + sr) * D_ + sq * 8;
  const _Float16* Wp = Wh + (size_t)sr * D_ + sq * 8;

  half8 ra0 = *reinterpret_cast<const half8*>(Ap);
  half8 ra1 = *reinterpret_cast<const half8*>(Ap + 32);
  half8 rw0 = *reinterpret_cast<const half8*>(Wp);
  half8 rw1 = *reinterpret_cast<const half8*>(Wp + 32);
  f32x4 acc[2][2] = {};

  for (int k0 = 0; k0 < D_; k0 += 64) {
    __syncthreads();
    *reinterpret_cast<half8*>(&As[sr][sq * 8]) = ra0;
    *reinterpret_cast<half8*>(&As[sr][32 + sq * 8]) = ra1;
    *reinterpret_cast<half8*>(&Bs[sr][sq * 8]) = rw0;
    *reinterpret_cast<half8*>(&Bs[sr][32 + sq * 8]) = rw1;
    __syncthreads();
    if (k0 + 64 < D_) {
      ra0 = *reinterpret_cast<const half8*>(Ap + k0 + 64);
      ra1 = *reinterpret_cast<const half8*>(Ap + k0 + 96);
      rw0 = *reinterpret_cast<const half8*>(Wp + k0 + 64);
      rw1 = *reinterpret_cast<const half8*>(Wp + k0 + 96);
    }
    half8 af[2][2], bf[2][2];
#pragma unroll
    for (int m = 0; m < 2; ++m)
#pragma unroll
      for (int s = 0; s < 2; ++s)
        af[m][s] = *reinterpret_cast<const half8*>(
            &As[wr * 32 + m * 16 + lr16][s * 32 + kq * 8]);
#pragma unroll
    for (int n = 0; n < 2; ++n)
#pragma unroll
      for (int s = 0; s < 2; ++s)
        bf[n][s] = *reinterpret_cast<const half8*>(
            &Bs[wc * 32 + n * 16 + lr16][s * 32 + kq * 8]);
#pragma unroll
    for (int m = 0; m < 2; ++m)
#pragma unroll
      for (int n = 0; n < 2; ++n)
#pragma unroll
        for (int s = 0; s < 2; ++s)
          acc[m][n] = __builtin_amdgcn_mfma_f32_16x16x32_f16(af[m][s], bf[n][s], acc[m][n], 0, 0, 0);
  }

#pragma unroll
  for (int m = 0; m < 2; ++m) {
#pragma unroll
    for (int n = 0; n < 2; ++n) {
      const int col = wc * 32 + n * 16 + lr16;
      if (col < MOTION_) {
        const float bb = bv[col];
#pragma unroll
        for (int j = 0; j < 4; ++j) {
          const int row = bm * 64 + wr * 32 + m * 16 + kq * 4 + j;
          float v = acc[m][n][j] + bb;
          Out[(size_t)row * MOTION_ + col] = fminf(fmaxf(v, 0.f), 1.f);
        }
      }
    }
  }
}

// ---------------------------------------------------------------------------
// x = shifted_motion @ W_vm.T + b_vm + PE(t%30); writes fp32 + fp16 mirror.
// ---------------------------------------------------------------------------
__global__ __launch_bounds__(256) void motion_pe(
    const float* __restrict__ TM, const float* __restrict__ Wvm,
    const float* __restrict__ bvm, float* __restrict__ Xout,
    _Float16* __restrict__ XoutH) {
  const int d = threadIdx.x;
  const int bt = blockIdx.x;
  const int t = bt & (T_ - 1);
  const int b = bt >> 10;
  float acc = bvm[d];
  if (t > 0) {
    const float* mrow = TM + ((size_t)b * T_ + t - 1) * MOTION_;
    const float* wrow = Wvm + (size_t)d * MOTION_;
#pragma unroll
    for (int m = 0; m < MOTION_; ++m) acc += mrow[m] * wrow[m];
  }
  const int pos = t % PERIOD_;
  const int i2 = d >> 1;
  const float div = expf((float)(2 * i2) * (-9.210340371976184f / 256.f));
  const float ang = (float)pos * div;
  acc += (d & 1) ? cosf(ang) : sinf(ang);
  Xout[(size_t)bt * D_ + d] = acc;
  XoutH[(size_t)bt * D_ + d] = (_Float16)acc;
}

// ---------------------------------------------------------------------------
// MFMA self-attention v2: QBLK=128, 512 threads / 8 waves.
// Each wave owns 16 queries (qloc = wave*16 + lo); the block shares each
// staged 64-key K/V tile across all 8 waves -> staging traffic and barrier
// rounds per query halve vs the 64-query version. Same fragment layouts,
// swapped QK^T, per-wave P LDS buffer, V^T XOR-scatter (proven r5-r8).
// ---------------------------------------------------------------------------
#define RS_ 72
__global__ __launch_bounds__(512) void self_attn(
    const _Float16* __restrict__ QKV, _Float16* __restrict__ O) {
  __shared__ _Float16 Ks[64 * RS_];
  __shared__ _Float16 VTs[64 * RS_];
  __shared__ _Float16 Ps[8][16 * RS_];
  const int qtb = blockIdx.x, h = blockIdx.y, b = blockIdx.z;
  const int tid = threadIdx.x;
  const int wave = tid >> 6, lane = tid & 63;
  const int lo = lane & 15, hi = lane >> 4;
  const float slope = exp2f(-2.f * (float)(h + 1));
  const int qloc = wave * 16 + lo;          // query within 128-tile
  const int tq = qtb * 128 + qloc;
  const size_t base = (size_t)b * T_ * 768 + h * 64;

  half8 qf[2];
#pragma unroll
  for (int s = 0; s < 2; ++s)
    qf[s] = *reinterpret_cast<const half8*>(
        QKV + base + (size_t)(qtb * 128 + qloc) * 768 + s * 32 + hi * 8);

  f32x4 oacc[4] = {};
  float mrun = -1e30f, lrun = 0.f;

  const int nkt = 2 * qtb + 2;  // causal 64-key tiles for this 128-query tile
  for (int kt = 0; kt < nkt; ++kt) {
    __syncthreads();
    {  // stage K row-major + V^T XOR-scattered; 512 threads, one pass
      const int j = tid >> 3, ch = tid & 7;
      const size_t rowoff = base + (size_t)(kt * 64 + j) * 768;
      *reinterpret_cast<half8*>(&Ks[j * RS_ + ch * 8]) =
          *reinterpret_cast<const half8*>(QKV + rowoff + 256 + ch * 8);
      const half8 vv = *reinterpret_cast<const half8*>(QKV + rowoff + 512 + ch * 8);
#pragma unroll
      for (int r = 0; r < 8; ++r) {
        const int d = ch * 8 + r;
        const int sw = ((d & 7) ^ (d >> 3)) << 3;
        VTs[d * RS_ + (j ^ sw)] = vv[r];
      }
    }
    __syncthreads();

    f32x4 st[4] = {};
#pragma unroll
    for (int f = 0; f < 4; ++f) {
#pragma unroll
      for (int s = 0; s < 2; ++s) {
        const half8 kf = *reinterpret_cast<const half8*>(
            &Ks[(f * 16 + lo) * RS_ + s * 32 + hi * 8]);
        st[f] = __builtin_amdgcn_mfma_f32_16x16x32_f16(kf, qf[s], st[f], 0, 0, 0);
      }
    }

    float sc[4][4];
    float tmax = -1e30f;
#pragma unroll
    for (int f = 0; f < 4; ++f)
#pragma unroll
      for (int r = 0; r < 4; ++r) {
        const int j = kt * 64 + f * 16 + hi * 4 + r;
        const int rel = tq - j;
        const float v = (rel >= 0)
            ? st[f][r] * 0.125f - slope * (float)(rel / PERIOD_) : -1e30f;
        sc[f][r] = v;
        tmax = fmaxf(tmax, v);
      }
    tmax = fmaxf(tmax, __shfl_xor(tmax, 16, 64));
    tmax = fmaxf(tmax, __shfl_xor(tmax, 32, 64));
    const float mnew = fmaxf(mrun, tmax);
    const float scale = __expf(mrun - mnew);

    float psum = 0.f;
#pragma unroll
    for (int f = 0; f < 4; ++f) {
      half4 ph;
#pragma unroll
      for (int r = 0; r < 4; ++r) {
        const float pv = __expf(sc[f][r] - mnew);
        psum += pv;
        ph[r] = (_Float16)pv;
      }
      *reinterpret_cast<half4*>(&Ps[wave][lo * RS_ + f * 16 + hi * 4]) = ph;
    }
    psum += __shfl_xor(psum, 16, 64);
    psum += __shfl_xor(psum, 32, 64);
    lrun = lrun * scale + psum;
    mrun = mnew;

    float rsc[4];
#pragma unroll
    for (int r = 0; r < 4; ++r) rsc[r] = __shfl(scale, hi * 4 + r, 64);
#pragma unroll
    for (int nf = 0; nf < 4; ++nf)
#pragma unroll
      for (int r = 0; r < 4; ++r) oacc[nf][r] *= rsc[r];

#pragma unroll
    for (int s = 0; s < 2; ++s) {
      const half8 pf = *reinterpret_cast<const half8*>(
          &Ps[wave][lo * RS_ + s * 32 + hi * 8]);
#pragma unroll
      for (int nf = 0; nf < 4; ++nf) {
        const int d = nf * 16 + lo;
        const int sw = ((d & 7) ^ (d >> 3)) << 3;
        const half8 vf = *reinterpret_cast<const half8*>(
            &VTs[d * RS_ + ((s * 32 + hi * 8) ^ sw)]);
        oacc[nf] = __builtin_amdgcn_mfma_f32_16x16x32_f16(pf, vf, oacc[nf], 0, 0, 0);
      }
    }
  }

  float invl[4];
#pragma unroll
  for (int r = 0; r < 4; ++r) invl[r] = 1.f / __shfl(lrun, hi * 4 + r, 64);
#pragma unroll
  for (int nf = 0; nf < 4; ++nf)
#pragma unroll
    for (int r = 0; r < 4; ++r) {
      const int q = qtb * 128 + wave * 16 + hi * 4 + r;
      O[((size_t)b * T_ + q) * D_ + h * 64 + nf * 16 + lo] =
          (_Float16)(oacc[nf][r] * invl[r]);
    }
}

// ---------------------------------------------------------------------------
// Banded cross-attention, fp16 q/kv inputs, fp16 output.
// ---------------------------------------------------------------------------
__global__ __launch_bounds__(256) void cross_attn(
    const _Float16* __restrict__ Q, const _Float16* __restrict__ KV,
    _Float16* __restrict__ O) {
  const int gid = blockIdx.x * 256 + threadIdx.x;
  const int h = gid & 3;
  const int bt = gid >> 2;
  const int t = bt & (T_ - 1);
  const int b = bt >> 10;

  float q[64];
  const _Float16* qp = Q + (size_t)bt * D_ + h * 64;
#pragma unroll
  for (int d0 = 0; d0 < 64; d0 += 8) {
    const half8 v = *reinterpret_cast<const half8*>(qp + d0);
#pragma unroll
    for (int e = 0; e < 8; ++e) q[d0 + e] = (float)v[e];
  }

  const int j0 = (t - WIN_ > 0) ? t - WIN_ : 0;
  const int j1 = (t + WIN_ < S_ - 1) ? t + WIN_ : S_ - 1;
  const int nj = j1 - j0 + 1;

  float sc[9];
  float mx = -1e30f;
#pragma unroll
  for (int jj = 0; jj < 9; ++jj) {
    if (jj < nj) {
      const _Float16* kp = KV + ((size_t)b * S_ + j0 + jj) * 512 + h * 64;
      float s = 0.f;
#pragma unroll
      for (int d0 = 0; d0 < 64; d0 += 8) {
        const half8 kv = *reinterpret_cast<const half8*>(kp + d0);
#pragma unroll
        for (int e = 0; e < 8; ++e) s += q[d0 + e] * (float)kv[e];
      }
      sc[jj] = s * 0.125f;
      mx = fmaxf(mx, sc[jj]);
    } else {
      sc[jj] = -1e30f;
    }
  }
  float l = 0.f;
  float p[9];
#pragma unroll
  for (int jj = 0; jj < 9; ++jj) { p[jj] = __expf(sc[jj] - mx); l += p[jj]; }
  const float inv = 1.f / l;

  float o[64];
#pragma unroll
  for (int d = 0; d < 64; ++d) o[d] = 0.f;
#pragma unroll
  for (int jj = 0; jj < 9; ++jj) {
    if (jj < nj) {
      const float pj = p[jj] * inv;
      const _Float16* vp = KV + ((size_t)b * S_ + j0 + jj) * 512 + 256 + h * 64;
#pragma unroll
      for (int d0 = 0; d0 < 64; d0 += 8) {
        const half8 vv = *reinterpret_cast<const half8*>(vp + d0);
#pragma unroll
        for (int e = 0; e < 8; ++e) o[d0 + e] += pj * (float)vv[e];
      }
    }
  }
  _Float16* op = O + (size_t)bt * D_ + h * 64;
#pragma unroll
  for (int d = 0; d < 64; ++d) op[d] = (_Float16)o[d];
}

// ---------------------------------------------------------------------------
// Out = LayerNorm(X + R) * g + b; writes fp32 + fp16 mirror. Out may == X.
// ---------------------------------------------------------------------------
__global__ __launch_bounds__(256) void ln_res(
    const float* X, const float* __restrict__ R,
    const float* __restrict__ g, const float* __restrict__ bta,
    float* Out, _Float16* __restrict__ OutH) {
  const int wid = threadIdx.x >> 6, lane = threadIdx.x & 63;
  const size_t row = (size_t)blockIdx.x * 4 + wid;
  const float* xp = X + row * D_;
  const float* rp = R + row * D_;
  float v[4];
  float s = 0.f;
#pragma unroll
  for (int k = 0; k < 4; ++k) {
    const int d = lane + k * 64;
    v[k] = xp[d] + rp[d];
    s += v[k];
  }
#pragma unroll
  for (int off = 32; off; off >>= 1) s += __shfl_xor(s, off, 64);
  const float mu = s * (1.f / 256.f);
  float var = 0.f;
#pragma unroll
  for (int k = 0; k < 4; ++k) { const float d = v[k] - mu; var += d * d; }
#pragma unroll
  for (int off = 32; off; off >>= 1) var += __shfl_xor(var, off, 64);
  const float rs = rsqrtf(var * (1.f / 256.f) + 1e-5f);
#pragma unroll
  for (int k = 0; k < 4; ++k) {
    const int d = lane + k * 64;
    const float o = (v[k] - mu) * rs * g[d] + bta[d];
    Out[row * D_ + d] = o;
    OutH[row * D_ + d] = (_Float16)o;
  }
}

// ---------------------------------------------------------------------------
extern "C" void kernel_launch(void* const* d_in, const int* in_sizes, int n_in,
                              void* d_out, int out_size, void* d_ws, size_t ws_size,
                              hipStream_t stream) {
  (void)in_sizes; (void)n_in; (void)out_size; (void)ws_size;
  const float* hidden = (const float*)d_in[0];
  const float* tmot   = (const float*)d_in[1];
  const float* W_af   = (const float*)d_in[2];
  const float* b_af   = (const float*)d_in[3];
  const float* c1w    = (const float*)d_in[4];
  const float* c1b    = (const float*)d_in[5];
  const float* c2w    = (const float*)d_in[6];
  const float* c2b    = (const float*)d_in[7];
  const float* Wvm    = (const float*)d_in[8];
  const float* bvm    = (const float*)d_in[9];
  const float* sa_in_w  = (const float*)d_in[10];
  const float* sa_in_b  = (const float*)d_in[11];
  const float* sa_out_w = (const float*)d_in[12];
  const float* sa_out_b = (const float*)d_in[13];
  const float* ca_in_w  = (const float*)d_in[14];
  const float* ca_in_b  = (const float*)d_in[15];
  const float* ca_out_w = (const float*)d_in[16];
  const float* ca_out_b = (const float*)d_in[17];
  const float* ln1g = (const float*)d_in[18];
  const float* ln1b = (const float*)d_in[19];
  const float* ln2g = (const float*)d_in[20];
  const float* ln2b = (const float*)d_in[21];
  const float* ln3g = (const float*)d_in[22];
  const float* ln3b = (const float*)d_in[23];
  const float* ff1w = (const float*)d_in[24];
  const float* ff1b = (const float*)d_in[25];
  const float* ff2w = (const float*)d_in[26];
  const float* ff2b = (const float*)d_in[27];
  const float* Wvr  = (const float*)d_in[28];
  const float* bvr  = (const float*)d_in[29];
  float* out = (float*)d_out;

  float* ws = (float*)d_ws;
  const size_t BSD = (size_t)M_ * D_;  // 2,097,152
  float* audio = ws;                    // fp32
  float* x     = ws + BSD;              // fp32
  float* t1    = ws + 2 * BSD;          // fp32
  _Float16* hb = (_Float16*)(ws + 3 * BSD);
  _Float16* Rh      = hb;               // 3*BSD halves, time-shared
  _Float16* x_h     = hb + 3 * BSD;
  _Float16* audio_h = hb + 4 * BSD;
  _Float16* att_h   = hb + 5 * BSD;
  _Float16* wH      = hb + 6 * BSD;     // WH_TOT halves
  _Float16* ckv_h   = Rh + BSD;

  const dim3 blk(256);

  // one-shot fp16 conversion: weights (+conv repack, +W_vr pad) and hidden
  CvtSrc cs;
  cs.p[0] = W_af;
  cs.p[1] = sa_in_w;            cs.p[2] = sa_in_w + 768 * 256;
  cs.p[3] = sa_out_w;           cs.p[4] = sa_out_w + 256 * 256;
  cs.p[5] = ca_in_w;            cs.p[6] = ca_in_w + 768 * 256;
  cs.p[7] = ca_out_w;           cs.p[8] = ca_out_w + 256 * 256;
  cs.p[9] = ff1w;               cs.p[10] = ff1w + 512 * 256;
  cs.p[11] = ff2w;              cs.p[12] = ff2w + 256 * 512;
  cs.p[13] = c1w;               cs.p[14] = c2w;
  cs.p[15] = hidden;            cs.p[16] = Wvr;
  cvt_all<<<dim3((WH_TOT + HID_TOT + 255) / 256), blk, 0, stream>>>(cs, wH, Rh);

  // audio front-end
  gemm_h<<<dim3(M_ / 64, 4), blk, 0, stream>>>(Rh, wH + O_AF, b_af, audio, audio_h,
                                               M_, 256, 768, 0);
  conv_h<<<dim3(128, 4), blk, 0, stream>>>(audio_h, wH + O_CONV1, c1b, Rh, nullptr, 0);
  conv_h<<<dim3(128, 4), blk, 0, stream>>>(Rh, wH + O_CONV2, c2b, audio_h, audio, 1);

  // motion embedding + PE
  motion_pe<<<dim3(M_), blk, 0, stream>>>(tmot, Wvm, bvm, x, x_h);

  for (int l = 0; l < 2; ++l) {
    // self-attention
    gemm_h<<<dim3(M_ / 64, 12), blk, 0, stream>>>(
        x_h, wH + O_SAIN + l * 196608, sa_in_b + l * 768, nullptr, Rh, M_, 768, 256, 0);
    self_attn<<<dim3(T_ / 128, H_, B_), dim3(512), 0, stream>>>(Rh, att_h);
    gemm_h<<<dim3(M_ / 64, 4), blk, 0, stream>>>(
        att_h, wH + O_SAOUT + l * 65536, sa_out_b + l * 256, t1, nullptr, M_, 256, 256, 0);
    ln_res<<<dim3(M_ / 4), blk, 0, stream>>>(x, t1, ln1g + l * 256, ln1b + l * 256, x, x_h);

    // cross-attention (banded)
    gemm_h<<<dim3(M_ / 64, 4), blk, 0, stream>>>(
        x_h, wH + O_CAIN + l * 196608, ca_in_b + l * 768, nullptr, Rh, M_, 256, 256, 0);
    gemm_h<<<dim3(M_ / 64, 8), blk, 0, stream>>>(
        audio_h, wH + O_CAIN + l * 196608 + 65536, ca_in_b + l * 768 + 256,
        nullptr, ckv_h, M_, 512, 256, 0);
    cross_attn<<<dim3(M_ * H_ / 256), blk, 0, stream>>>(Rh, ckv_h, att_h);
    gemm_h<<<dim3(M_ / 64, 4), blk, 0, stream>>>(
        att_h, wH + O_CAOUT + l * 65536, ca_out_b + l * 256, t1, nullptr, M_, 256, 256, 0);
    ln_res<<<dim3(M_ / 4), blk, 0, stream>>>(x, t1, ln2g + l * 256, ln2b + l * 256, x, x_h);

    // FFN
    gemm_h<<<dim3(M_ / 64, 8), blk, 0, stream>>>(
        x_h, wH + O_FF1 + l * 131072, ff1b + l * 512, nullptr, Rh, M_, 512, 256, 1);
    gemm_h<<<dim3(M_ / 64, 4), blk, 0, stream>>>(
        Rh, wH + O_FF2 + l * 131072, ff2b + l * 256, t1, nullptr, M_, 256, 512, 0);
    ln_res<<<dim3(M_ / 4), blk, 0, stream>>>(x, t1, ln3g + l * 256, ln3b + l * 256, x, x_h);
  }

  head_mfma<<<dim3(M_ / 64), blk, 0, stream>>>(x_h, wH + O_VR, bvr, out);
}

// Round 10
// 359.806 us; speedup vs baseline: 1.7719x; 1.0170x over previous
//
#include <hip/hip_runtime.h>
#include <math.h>

#define B_ 8
#define T_ 1024
#define S_ 1024
#define D_ 256
#define H_ 4
#define DH_ 64
#define AUDIO_ 768
#define MOTION_ 33
#define PERIOD_ 30
#define WIN_ 4
#define M_ (B_ * T_)

typedef _Float16 half8 __attribute__((ext_vector_type(8)));
typedef _Float16 half4 __attribute__((ext_vector_type(4)));
typedef __attribute__((ext_vector_type(4))) float f32x4;

// fp16 weight arena offsets (halves)
#define O_AF    0
#define O_SAIN  196608   // + l*196608
#define O_SAOUT 589824   // + l*65536
#define O_CAIN  720896   // + l*196608
#define O_CAOUT 1114112  // + l*65536
#define O_FF1   1245184  // + l*131072
#define O_FF2   1507328  // + l*131072
#define O_CONV1 1769472
#define O_CONV2 2097152
#define O_VR    2424832  // W_vr padded to 64x256
#define WH_TOT  2441216
#define HID_TOT 6291456  // 8192*768

struct CvtSrc { const float* p[17]; };

// ---------------------------------------------------------------------------
// One-shot fp32->fp16 conversion of all weights (+ conv repack to
// [oc][tap*256+cin], + W_vr zero-padded to 64 rows) and hidden_states.
// ---------------------------------------------------------------------------
__global__ __launch_bounds__(256) void cvt_all(
    CvtSrc s, _Float16* __restrict__ wH, _Float16* __restrict__ hidH) {
  const long i = (long)blockIdx.x * 256 + threadIdx.x;
  if (i >= (long)WH_TOT + HID_TOT) return;
  if (i >= WH_TOT) { const long j = i - WH_TOT; hidH[j] = (_Float16)s.p[15][j]; return; }
  if (i >= O_VR) {
    const long j = i - O_VR, oc = j >> 8, cin = j & 255;
    wH[i] = (oc < MOTION_) ? (_Float16)s.p[16][oc * 256 + cin] : (_Float16)0.f;
    return;
  }
  if (i >= O_CONV2) {
    const long j = i - O_CONV2, oc = j / 1280, r = j % 1280, tap = r >> 8, cin = r & 255;
    wH[i] = (_Float16)s.p[14][(oc * 256 + cin) * 5 + tap]; return;
  }
  if (i >= O_CONV1) {
    const long j = i - O_CONV1, oc = j / 1280, r = j % 1280, tap = r >> 8, cin = r & 255;
    wH[i] = (_Float16)s.p[13][(oc * 256 + cin) * 5 + tap]; return;
  }
  int seg; long base;
  if      (i >= 1638400) { seg = 12; base = 1638400; }
  else if (i >= 1507328) { seg = 11; base = 1507328; }
  else if (i >= 1376256) { seg = 10; base = 1376256; }
  else if (i >= 1245184) { seg = 9;  base = 1245184; }
  else if (i >= 1179648) { seg = 8;  base = 1179648; }
  else if (i >= 1114112) { seg = 7;  base = 1114112; }
  else if (i >= 917504)  { seg = 6;  base = 917504; }
  else if (i >= 720896)  { seg = 5;  base = 720896; }
  else if (i >= 655360)  { seg = 4;  base = 655360; }
  else if (i >= 589824)  { seg = 3;  base = 589824; }
  else if (i >= 393216)  { seg = 2;  base = 393216; }
  else if (i >= 196608)  { seg = 1;  base = 196608; }
  else                   { seg = 0;  base = 0; }
  wH[i] = (_Float16)s.p[seg][i - base];
}

// ---------------------------------------------------------------------------
// fp16 GEMM: C = A @ W.T + bias. Tile 64x64, BK=64, register prefetch.
// ---------------------------------------------------------------------------
__global__ __launch_bounds__(256) void gemm_h(
    const _Float16* __restrict__ A, const _Float16* __restrict__ W,
    const float* __restrict__ bias, float* __restrict__ Cf,
    _Float16* __restrict__ Ch, int M, int N, int K, int relu) {
  __shared__ _Float16 As[64][72];
  __shared__ _Float16 Bs[64][72];
  const int tid = threadIdx.x;
  const int wave = tid >> 6, lane = tid & 63;
  const int wr = wave >> 1, wc = wave & 1;
  const int lr16 = lane & 15, kq = lane >> 4;
  const int bm = blockIdx.x, bn = blockIdx.y;
  const int sr = tid >> 2, sq = tid & 3;

  const _Float16* Ap = A + (size_t)(bm * 64 + sr) * K + sq * 8;
  const _Float16* Wp = W + (size_t)(bn * 64 + sr) * K + sq * 8;

  half8 ra0 = *reinterpret_cast<const half8*>(Ap);
  half8 ra1 = *reinterpret_cast<const half8*>(Ap + 32);
  half8 rw0 = *reinterpret_cast<const half8*>(Wp);
  half8 rw1 = *reinterpret_cast<const half8*>(Wp + 32);
  f32x4 acc[2][2] = {};

  for (int k0 = 0; k0 < K; k0 += 64) {
    __syncthreads();
    *reinterpret_cast<half8*>(&As[sr][sq * 8]) = ra0;
    *reinterpret_cast<half8*>(&As[sr][32 + sq * 8]) = ra1;
    *reinterpret_cast<half8*>(&Bs[sr][sq * 8]) = rw0;
    *reinterpret_cast<half8*>(&Bs[sr][32 + sq * 8]) = rw1;
    __syncthreads();
    if (k0 + 64 < K) {
      ra0 = *reinterpret_cast<const half8*>(Ap + k0 + 64);
      ra1 = *reinterpret_cast<const half8*>(Ap + k0 + 96);
      rw0 = *reinterpret_cast<const half8*>(Wp + k0 + 64);
      rw1 = *reinterpret_cast<const half8*>(Wp + k0 + 96);
    }
    half8 af[2][2], bf[2][2];
#pragma unroll
    for (int m = 0; m < 2; ++m)
#pragma unroll
      for (int s = 0; s < 2; ++s)
        af[m][s] = *reinterpret_cast<const half8*>(
            &As[wr * 32 + m * 16 + lr16][s * 32 + kq * 8]);
#pragma unroll
    for (int n = 0; n < 2; ++n)
#pragma unroll
      for (int s = 0; s < 2; ++s)
        bf[n][s] = *reinterpret_cast<const half8*>(
            &Bs[wc * 32 + n * 16 + lr16][s * 32 + kq * 8]);
#pragma unroll
    for (int m = 0; m < 2; ++m)
#pragma unroll
      for (int n = 0; n < 2; ++n)
#pragma unroll
        for (int s = 0; s < 2; ++s)
          acc[m][n] = __builtin_amdgcn_mfma_f32_16x16x32_f16(af[m][s], bf[n][s], acc[m][n], 0, 0, 0);
  }

#pragma unroll
  for (int m = 0; m < 2; ++m) {
#pragma unroll
    for (int n = 0; n < 2; ++n) {
      const int col = bn * 64 + wc * 32 + n * 16 + lr16;
      const float bv = bias[col];
#pragma unroll
      for (int j = 0; j < 4; ++j) {
        const int row = bm * 64 + wr * 32 + m * 16 + kq * 4 + j;
        float v = acc[m][n][j] + bv;
        if (relu) v = fmaxf(v, 0.f);
        const size_t idx = (size_t)row * N + col;
        if (Cf) Cf[idx] = v;
        if (Ch) Ch[idx] = (_Float16)v;
      }
    }
  }
}

// ---------------------------------------------------------------------------
// Conv1d k=5 as fp16 GEMM, K=1280 tap-major repacked weights, BK=64.
// ---------------------------------------------------------------------------
__device__ __forceinline__ half8 conv_ld(const _Float16* Xb, int p, int tap, int cin) {
  const int sp = p + tap - 2;
  if (sp < 0 || sp >= S_) { half8 z = {}; return z; }
  return *reinterpret_cast<const half8*>(Xb + (size_t)sp * D_ + cin);
}

__global__ __launch_bounds__(256) void conv_h(
    const _Float16* __restrict__ Xh, const _Float16* __restrict__ Wc,
    const float* __restrict__ bias, _Float16* __restrict__ OutH,
    const float* __restrict__ ResF, int mode) {
  __shared__ _Float16 As[64][72];
  __shared__ _Float16 Bs[64][72];
  const int tid = threadIdx.x;
  const int wave = tid >> 6, lane = tid & 63;
  const int wr = wave >> 1, wc = wave & 1;
  const int lr16 = lane & 15, kq = lane >> 4;
  const int b = blockIdx.x >> 4;
  const int s0 = (blockIdx.x & 15) * 64;
  const int o0 = blockIdx.y * 64;
  const int sr = tid >> 2, sq = tid & 3;

  const _Float16* Xb = Xh + (size_t)b * S_ * D_;
  const _Float16* Wp = Wc + (size_t)(o0 + sr) * 1280 + sq * 8;
  const int p = s0 + sr;

  half8 ra0 = conv_ld(Xb, p, 0, sq * 8);
  half8 ra1 = conv_ld(Xb, p, 0, 32 + sq * 8);
  half8 rw0 = *reinterpret_cast<const half8*>(Wp);
  half8 rw1 = *reinterpret_cast<const half8*>(Wp + 32);
  f32x4 acc[2][2] = {};

  for (int k0 = 0; k0 < 1280; k0 += 64) {
    __syncthreads();
    *reinterpret_cast<half8*>(&As[sr][sq * 8]) = ra0;
    *reinterpret_cast<half8*>(&As[sr][32 + sq * 8]) = ra1;
    *reinterpret_cast<half8*>(&Bs[sr][sq * 8]) = rw0;
    *reinterpret_cast<half8*>(&Bs[sr][32 + sq * 8]) = rw1;
    __syncthreads();
    if (k0 + 64 < 1280) {
      const int kn = k0 + 64;
      const int tap = kn >> 8, cb = kn & 255;
      ra0 = conv_ld(Xb, p, tap, cb + sq * 8);
      ra1 = conv_ld(Xb, p, tap, cb + 32 + sq * 8);
      rw0 = *reinterpret_cast<const half8*>(Wp + kn);
      rw1 = *reinterpret_cast<const half8*>(Wp + kn + 32);
    }
    half8 af[2][2], bf[2][2];
#pragma unroll
    for (int m = 0; m < 2; ++m)
#pragma unroll
      for (int s = 0; s < 2; ++s)
        af[m][s] = *reinterpret_cast<const half8*>(
            &As[wr * 32 + m * 16 + lr16][s * 32 + kq * 8]);
#pragma unroll
    for (int n = 0; n < 2; ++n)
#pragma unroll
      for (int s = 0; s < 2; ++s)
        bf[n][s] = *reinterpret_cast<const half8*>(
            &Bs[wc * 32 + n * 16 + lr16][s * 32 + kq * 8]);
#pragma unroll
    for (int m = 0; m < 2; ++m)
#pragma unroll
      for (int n = 0; n < 2; ++n)
#pragma unroll
        for (int s = 0; s < 2; ++s)
          acc[m][n] = __builtin_amdgcn_mfma_f32_16x16x32_f16(af[m][s], bf[n][s], acc[m][n], 0, 0, 0);
  }

#pragma unroll
  for (int m = 0; m < 2; ++m) {
#pragma unroll
    for (int n = 0; n < 2; ++n) {
      const int oc = o0 + wc * 32 + n * 16 + lr16;
      const float bv = bias[oc];
#pragma unroll
      for (int j = 0; j < 4; ++j) {
        const int s = s0 + wr * 32 + m * 16 + kq * 4 + j;
        const size_t idx = ((size_t)b * S_ + s) * D_ + oc;
        float v = acc[m][n][j] + bv;
        if (mode == 0) {
          v = 0.5f * v * (1.f + erff(v * 0.70710678118654752f));
        } else {
          v += ResF[idx];
        }
        OutH[idx] = (_Float16)v;
      }
    }
  }
}

// ---------------------------------------------------------------------------
// Head: out = clip(x @ W_vr.T + b_vr, 0, 1) via MFMA (W_vr padded to 64).
// ---------------------------------------------------------------------------
__global__ __launch_bounds__(256) void head_mfma(
    const _Float16* __restrict__ Xh, const _Float16* __restrict__ Wh,
    const float* __restrict__ bv, float* __restrict__ Out) {
  __shared__ _Float16 As[64][72];
  __shared__ _Float16 Bs[64][72];
  const int tid = threadIdx.x;
  const int wave = tid >> 6, lane = tid & 63;
  const int wr = wave >> 1, wc = wave & 1;
  const int lr16 = lane & 15, kq = lane >> 4;
  const int bm = blockIdx.x;
  const int sr = tid >> 2, sq = tid & 3;

  const _Float16* Ap = Xh + (size_t)(bm * 64 + sr) * D_ + sq * 8;
  const _Float16* Wp = Wh + (size_t)sr * D_ + sq * 8;

  half8 ra0 = *reinterpret_cast<const half8*>(Ap);
  half8 ra1 = *reinterpret_cast<const half8*>(Ap + 32);
  half8 rw0 = *reinterpret_cast<const half8*>(Wp);
  half8 rw1 = *reinterpret_cast<const half8*>(Wp + 32);
  f32x4 acc[2][2] = {};

  for (int k0 = 0; k0 < D_; k0 += 64) {
    __syncthreads();
    *reinterpret_cast<half8*>(&As[sr][sq * 8]) = ra0;
    *reinterpret_cast<half8*>(&As[sr][32 + sq * 8]) = ra1;
    *reinterpret_cast<half8*>(&Bs[sr][sq * 8]) = rw0;
    *reinterpret_cast<half8*>(&Bs[sr][32 + sq * 8]) = rw1;
    __syncthreads();
    if (k0 + 64 < D_) {
      ra0 = *reinterpret_cast<const half8*>(Ap + k0 + 64);
      ra1 = *reinterpret_cast<const half8*>(Ap + k0 + 96);
      rw0 = *reinterpret_cast<const half8*>(Wp + k0 + 64);
      rw1 = *reinterpret_cast<const half8*>(Wp + k0 + 96);
    }
    half8 af[2][2], bf[2][2];
#pragma unroll
    for (int m = 0; m < 2; ++m)
#pragma unroll
      for (int s = 0; s < 2; ++s)
        af[m][s] = *reinterpret_cast<const half8*>(
            &As[wr * 32 + m * 16 + lr16][s * 32 + kq * 8]);
#pragma unroll
    for (int n = 0; n < 2; ++n)
#pragma unroll
      for (int s = 0; s < 2; ++s)
        bf[n][s] = *reinterpret_cast<const half8*>(
            &Bs[wc * 32 + n * 16 + lr16][s * 32 + kq * 8]);
#pragma unroll
    for (int m = 0; m < 2; ++m)
#pragma unroll
      for (int n = 0; n < 2; ++n)
#pragma unroll
        for (int s = 0; s < 2; ++s)
          acc[m][n] = __builtin_amdgcn_mfma_f32_16x16x32_f16(af[m][s], bf[n][s], acc[m][n], 0, 0, 0);
  }

#pragma unroll
  for (int m = 0; m < 2; ++m) {
#pragma unroll
    for (int n = 0; n < 2; ++n) {
      const int col = wc * 32 + n * 16 + lr16;
      if (col < MOTION_) {
        const float bb = bv[col];
#pragma unroll
        for (int j = 0; j < 4; ++j) {
          const int row = bm * 64 + wr * 32 + m * 16 + kq * 4 + j;
          float v = acc[m][n][j] + bb;
          Out[(size_t)row * MOTION_ + col] = fminf(fmaxf(v, 0.f), 1.f);
        }
      }
    }
  }
}

// ---------------------------------------------------------------------------
// x = shifted_motion @ W_vm.T + b_vm + PE(t%30); writes fp32 + fp16 mirror.
// ---------------------------------------------------------------------------
__global__ __launch_bounds__(256) void motion_pe(
    const float* __restrict__ TM, const float* __restrict__ Wvm,
    const float* __restrict__ bvm, float* __restrict__ Xout,
    _Float16* __restrict__ XoutH) {
  const int d = threadIdx.x;
  const int bt = blockIdx.x;
  const int t = bt & (T_ - 1);
  const int b = bt >> 10;
  float acc = bvm[d];
  if (t > 0) {
    const float* mrow = TM + ((size_t)b * T_ + t - 1) * MOTION_;
    const float* wrow = Wvm + (size_t)d * MOTION_;
#pragma unroll
    for (int m = 0; m < MOTION_; ++m) acc += mrow[m] * wrow[m];
  }
  const int pos = t % PERIOD_;
  const int i2 = d >> 1;
  const float div = expf((float)(2 * i2) * (-9.210340371976184f / 256.f));
  const float ang = (float)pos * div;
  acc += (d & 1) ? cosf(ang) : sinf(ang);
  Xout[(size_t)bt * D_ + d] = acc;
  XoutH[(size_t)bt * D_ + d] = (_Float16)acc;
}

// ---------------------------------------------------------------------------
// MFMA self-attention v3: QBLK=128, 512 thr / 8 waves, DOUBLE-BUFFERED K/V.
// Per tile: issue next-tile global loads to regs, compute current tile from
// LDS, write regs to the other buffer, ONE barrier. Global latency hides
// under QK/softmax/PV; barrier count halves vs v2.
// Bank layout: Ks stride 72 (row term spreads banks; read/write balanced),
// VTs stride 64 (128 B == 0 mod 32 dwords, so its XOR swizzle alone
// determines the bank -> scatter-writes and b128 reads both balanced; the
// old stride-72 + XOR combo degenerated to a 1-group hotspot).
// ---------------------------------------------------------------------------
#define RSK_ 72
#define RSV_ 64
__global__ __launch_bounds__(512) void self_attn(
    const _Float16* __restrict__ QKV, _Float16* __restrict__ O) {
  __shared__ _Float16 Ks[2][64 * RSK_];
  __shared__ _Float16 VTs[2][64 * RSV_];
  __shared__ _Float16 Ps[8][16 * RSK_];
  const int qtb = blockIdx.x, h = blockIdx.y, b = blockIdx.z;
  const int tid = threadIdx.x;
  const int wave = tid >> 6, lane = tid & 63;
  const int lo = lane & 15, hi = lane >> 4;
  const float slope = exp2f(-2.f * (float)(h + 1));
  const int qloc = wave * 16 + lo;
  const int tq = qtb * 128 + qloc;
  const size_t base = (size_t)b * T_ * 768 + h * 64;
  const int sj = tid >> 3, sch = tid & 7;   // staging coords (row, 8-col chunk)

  half8 qf[2];
#pragma unroll
  for (int s = 0; s < 2; ++s)
    qf[s] = *reinterpret_cast<const half8*>(
        QKV + base + (size_t)(qtb * 128 + qloc) * 768 + s * 32 + hi * 8);

  f32x4 oacc[4] = {};
  float mrun = -1e30f, lrun = 0.f;

  const int nkt = 2 * qtb + 2;

  // prologue: stage tile 0 into buffer 0
  half8 rk, rv;
  {
    const size_t rowoff = base + (size_t)sj * 768;
    rk = *reinterpret_cast<const half8*>(QKV + rowoff + 256 + sch * 8);
    rv = *reinterpret_cast<const half8*>(QKV + rowoff + 512 + sch * 8);
    *reinterpret_cast<half8*>(&Ks[0][sj * RSK_ + sch * 8]) = rk;
#pragma unroll
    for (int r = 0; r < 8; ++r) {
      const int d = sch * 8 + r;
      const int sw = ((d & 7) ^ (d >> 3)) << 3;
      VTs[0][d * RSV_ + (sj ^ sw)] = rv[r];
    }
  }
  __syncthreads();

  for (int kt = 0; kt < nkt; ++kt) {
    const int cur = kt & 1;
    const bool more = (kt + 1 < nkt);
    if (more) {  // issue next-tile loads early; vmcnt waits only at ds_write
      const size_t rowoff = base + (size_t)((kt + 1) * 64 + sj) * 768;
      rk = *reinterpret_cast<const half8*>(QKV + rowoff + 256 + sch * 8);
      rv = *reinterpret_cast<const half8*>(QKV + rowoff + 512 + sch * 8);
    }

    // ---- compute tile kt from buffers [cur] ----
    f32x4 st[4] = {};
#pragma unroll
    for (int f = 0; f < 4; ++f) {
#pragma unroll
      for (int s = 0; s < 2; ++s) {
        const half8 kf = *reinterpret_cast<const half8*>(
            &Ks[cur][(f * 16 + lo) * RSK_ + s * 32 + hi * 8]);
        st[f] = __builtin_amdgcn_mfma_f32_16x16x32_f16(kf, qf[s], st[f], 0, 0, 0);
      }
    }

    float sc[4][4];
    float tmax = -1e30f;
#pragma unroll
    for (int f = 0; f < 4; ++f)
#pragma unroll
      for (int r = 0; r < 4; ++r) {
        const int j = kt * 64 + f * 16 + hi * 4 + r;
        const int rel = tq - j;
        const float v = (rel >= 0)
            ? st[f][r] * 0.125f - slope * (float)(rel / PERIOD_) : -1e30f;
        sc[f][r] = v;
        tmax = fmaxf(tmax, v);
      }
    tmax = fmaxf(tmax, __shfl_xor(tmax, 16, 64));
    tmax = fmaxf(tmax, __shfl_xor(tmax, 32, 64));
    const float mnew = fmaxf(mrun, tmax);
    const float scale = __expf(mrun - mnew);

    float psum = 0.f;
#pragma unroll
    for (int f = 0; f < 4; ++f) {
      half4 ph;
#pragma unroll
      for (int r = 0; r < 4; ++r) {
        const float pv = __expf(sc[f][r] - mnew);
        psum += pv;
        ph[r] = (_Float16)pv;
      }
      *reinterpret_cast<half4*>(&Ps[wave][lo * RSK_ + f * 16 + hi * 4]) = ph;
    }
    psum += __shfl_xor(psum, 16, 64);
    psum += __shfl_xor(psum, 32, 64);
    lrun = lrun * scale + psum;
    mrun = mnew;

    float rsc[4];
#pragma unroll
    for (int r = 0; r < 4; ++r) rsc[r] = __shfl(scale, hi * 4 + r, 64);
#pragma unroll
    for (int nf = 0; nf < 4; ++nf)
#pragma unroll
      for (int r = 0; r < 4; ++r) oacc[nf][r] *= rsc[r];

#pragma unroll
    for (int s = 0; s < 2; ++s) {
      const half8 pf = *reinterpret_cast<const half8*>(
          &Ps[wave][lo * RSK_ + s * 32 + hi * 8]);
#pragma unroll
      for (int nf = 0; nf < 4; ++nf) {
        const int d = nf * 16 + lo;
        const int sw = ((d & 7) ^ (d >> 3)) << 3;
        const half8 vf = *reinterpret_cast<const half8*>(
            &VTs[cur][d * RSV_ + ((s * 32 + hi * 8) ^ sw)]);
        oacc[nf] = __builtin_amdgcn_mfma_f32_16x16x32_f16(pf, vf, oacc[nf], 0, 0, 0);
      }
    }

    // ---- write next tile into the other buffer; one barrier per tile ----
    if (more) {
      *reinterpret_cast<half8*>(&Ks[cur ^ 1][sj * RSK_ + sch * 8]) = rk;
#pragma unroll
      for (int r = 0; r < 8; ++r) {
        const int d = sch * 8 + r;
        const int sw = ((d & 7) ^ (d >> 3)) << 3;
        VTs[cur ^ 1][d * RSV_ + (sj ^ sw)] = rv[r];
      }
      __syncthreads();
    }
  }

  float invl[4];
#pragma unroll
  for (int r = 0; r < 4; ++r) invl[r] = 1.f / __shfl(lrun, hi * 4 + r, 64);
#pragma unroll
  for (int nf = 0; nf < 4; ++nf)
#pragma unroll
    for (int r = 0; r < 4; ++r) {
      const int q = qtb * 128 + wave * 16 + hi * 4 + r;
      O[((size_t)b * T_ + q) * D_ + h * 64 + nf * 16 + lo] =
          (_Float16)(oacc[nf][r] * invl[r]);
    }
}

// ---------------------------------------------------------------------------
// Banded cross-attention, fp16 q/kv inputs, fp16 output.
// ---------------------------------------------------------------------------
__global__ __launch_bounds__(256) void cross_attn(
    const _Float16* __restrict__ Q, const _Float16* __restrict__ KV,
    _Float16* __restrict__ O) {
  const int gid = blockIdx.x * 256 + threadIdx.x;
  const int h = gid & 3;
  const int bt = gid >> 2;
  const int t = bt & (T_ - 1);
  const int b = bt >> 10;

  float q[64];
  const _Float16* qp = Q + (size_t)bt * D_ + h * 64;
#pragma unroll
  for (int d0 = 0; d0 < 64; d0 += 8) {
    const half8 v = *reinterpret_cast<const half8*>(qp + d0);
#pragma unroll
    for (int e = 0; e < 8; ++e) q[d0 + e] = (float)v[e];
  }

  const int j0 = (t - WIN_ > 0) ? t - WIN_ : 0;
  const int j1 = (t + WIN_ < S_ - 1) ? t + WIN_ : S_ - 1;
  const int nj = j1 - j0 + 1;

  float sc[9];
  float mx = -1e30f;
#pragma unroll
  for (int jj = 0; jj < 9; ++jj) {
    if (jj < nj) {
      const _Float16* kp = KV + ((size_t)b * S_ + j0 + jj) * 512 + h * 64;
      float s = 0.f;
#pragma unroll
      for (int d0 = 0; d0 < 64; d0 += 8) {
        const half8 kv = *reinterpret_cast<const half8*>(kp + d0);
#pragma unroll
        for (int e = 0; e < 8; ++e) s += q[d0 + e] * (float)kv[e];
      }
      sc[jj] = s * 0.125f;
      mx = fmaxf(mx, sc[jj]);
    } else {
      sc[jj] = -1e30f;
    }
  }
  float l = 0.f;
  float p[9];
#pragma unroll
  for (int jj = 0; jj < 9; ++jj) { p[jj] = __expf(sc[jj] - mx); l += p[jj]; }
  const float inv = 1.f / l;

  float o[64];
#pragma unroll
  for (int d = 0; d < 64; ++d) o[d] = 0.f;
#pragma unroll
  for (int jj = 0; jj < 9; ++jj) {
    if (jj < nj) {
      const float pj = p[jj] * inv;
      const _Float16* vp = KV + ((size_t)b * S_ + j0 + jj) * 512 + 256 + h * 64;
#pragma unroll
      for (int d0 = 0; d0 < 64; d0 += 8) {
        const half8 vv = *reinterpret_cast<const half8*>(vp + d0);
#pragma unroll
        for (int e = 0; e < 8; ++e) o[d0 + e] += pj * (float)vv[e];
      }
    }
  }
  _Float16* op = O + (size_t)bt * D_ + h * 64;
#pragma unroll
  for (int d = 0; d < 64; ++d) op[d] = (_Float16)o[d];
}

// ---------------------------------------------------------------------------
// Out = LayerNorm(X + R) * g + b; writes fp32 + fp16 mirror. Out may == X.
// ---------------------------------------------------------------------------
__global__ __launch_bounds__(256) void ln_res(
    const float* X, const float* __restrict__ R,
    const float* __restrict__ g, const float* __restrict__ bta,
    float* Out, _Float16* __restrict__ OutH) {
  const int wid = threadIdx.x >> 6, lane = threadIdx.x & 63;
  const size_t row = (size_t)blockIdx.x * 4 + wid;
  const float* xp = X + row * D_;
  const float* rp = R + row * D_;
  float v[4];
  float s = 0.f;
#pragma unroll
  for (int k = 0; k < 4; ++k) {
    const int d = lane + k * 64;
    v[k] = xp[d] + rp[d];
    s += v[k];
  }
#pragma unroll
  for (int off = 32; off; off >>= 1) s += __shfl_xor(s, off, 64);
  const float mu = s * (1.f / 256.f);
  float var = 0.f;
#pragma unroll
  for (int k = 0; k < 4; ++k) { const float d = v[k] - mu; var += d * d; }
#pragma unroll
  for (int off = 32; off; off >>= 1) var += __shfl_xor(var, off, 64);
  const float rs = rsqrtf(var * (1.f / 256.f) + 1e-5f);
#pragma unroll
  for (int k = 0; k < 4; ++k) {
    const int d = lane + k * 64;
    const float o = (v[k] - mu) * rs * g[d] + bta[d];
    Out[row * D_ + d] = o;
    OutH[row * D_ + d] = (_Float16)o;
  }
}

// ---------------------------------------------------------------------------
extern "C" void kernel_launch(void* const* d_in, const int* in_sizes, int n_in,
                              void* d_out, int out_size, void* d_ws, size_t ws_size,
                              hipStream_t stream) {
  (void)in_sizes; (void)n_in; (void)out_size; (void)ws_size;
  const float* hidden = (const float*)d_in[0];
  const float* tmot   = (const float*)d_in[1];
  const float* W_af   = (const float*)d_in[2];
  const float* b_af   = (const float*)d_in[3];
  const float* c1w    = (const float*)d_in[4];
  const float* c1b    = (const float*)d_in[5];
  const float* c2w    = (const float*)d_in[6];
  const float* c2b    = (const float*)d_in[7];
  const float* Wvm    = (const float*)d_in[8];
  const float* bvm    = (const float*)d_in[9];
  const float* sa_in_w  = (const float*)d_in[10];
  const float* sa_in_b  = (const float*)d_in[11];
  const float* sa_out_w = (const float*)d_in[12];
  const float* sa_out_b = (const float*)d_in[13];
  const float* ca_in_w  = (const float*)d_in[14];
  const float* ca_in_b  = (const float*)d_in[15];
  const float* ca_out_w = (const float*)d_in[16];
  const float* ca_out_b = (const float*)d_in[17];
  const float* ln1g = (const float*)d_in[18];
  const float* ln1b = (const float*)d_in[19];
  const float* ln2g = (const float*)d_in[20];
  const float* ln2b = (const float*)d_in[21];
  const float* ln3g = (const float*)d_in[22];
  const float* ln3b = (const float*)d_in[23];
  const float* ff1w = (const float*)d_in[24];
  const float* ff1b = (const float*)d_in[25];
  const float* ff2w = (const float*)d_in[26];
  const float* ff2b = (const float*)d_in[27];
  const float* Wvr  = (const float*)d_in[28];
  const float* bvr  = (const float*)d_in[29];
  float* out = (float*)d_out;

  float* ws = (float*)d_ws;
  const size_t BSD = (size_t)M_ * D_;  // 2,097,152
  float* audio = ws;                    // fp32
  float* x     = ws + BSD;              // fp32
  float* t1    = ws + 2 * BSD;          // fp32
  _Float16* hb = (_Float16*)(ws + 3 * BSD);
  _Float16* Rh      = hb;               // 3*BSD halves, time-shared
  _Float16* x_h     = hb + 3 * BSD;
  _Float16* audio_h = hb + 4 * BSD;
  _Float16* att_h   = hb + 5 * BSD;
  _Float16* wH      = hb + 6 * BSD;     // WH_TOT halves
  _Float16* ckv_h   = Rh + BSD;

  const dim3 blk(256);

  // one-shot fp16 conversion: weights (+conv repack, +W_vr pad) and hidden
  CvtSrc cs;
  cs.p[0] = W_af;
  cs.p[1] = sa_in_w;            cs.p[2] = sa_in_w + 768 * 256;
  cs.p[3] = sa_out_w;           cs.p[4] = sa_out_w + 256 * 256;
  cs.p[5] = ca_in_w;            cs.p[6] = ca_in_w + 768 * 256;
  cs.p[7] = ca_out_w;           cs.p[8] = ca_out_w + 256 * 256;
  cs.p[9] = ff1w;               cs.p[10] = ff1w + 512 * 256;
  cs.p[11] = ff2w;              cs.p[12] = ff2w + 256 * 512;
  cs.p[13] = c1w;               cs.p[14] = c2w;
  cs.p[15] = hidden;            cs.p[16] = Wvr;
  cvt_all<<<dim3((WH_TOT + HID_TOT + 255) / 256), blk, 0, stream>>>(cs, wH, Rh);

  // audio front-end
  gemm_h<<<dim3(M_ / 64, 4), blk, 0, stream>>>(Rh, wH + O_AF, b_af, audio, audio_h,
                                               M_, 256, 768, 0);
  conv_h<<<dim3(128, 4), blk, 0, stream>>>(audio_h, wH + O_CONV1, c1b, Rh, nullptr, 0);
  conv_h<<<dim3(128, 4), blk, 0, stream>>>(Rh, wH + O_CONV2, c2b, audio_h, audio, 1);

  // motion embedding + PE
  motion_pe<<<dim3(M_), blk, 0, stream>>>(tmot, Wvm, bvm, x, x_h);

  for (int l = 0; l < 2; ++l) {
    // self-attention
    gemm_h<<<dim3(M_ / 64, 12), blk, 0, stream>>>(
        x_h, wH + O_SAIN + l * 196608, sa_in_b + l * 768, nullptr, Rh, M_, 768, 256, 0);
    self_attn<<<dim3(T_ / 128, H_, B_), dim3(512), 0, stream>>>(Rh, att_h);
    gemm_h<<<dim3(M_ / 64, 4), blk, 0, stream>>>(
        att_h, wH + O_SAOUT + l * 65536, sa_out_b + l * 256, t1, nullptr, M_, 256, 256, 0);
    ln_res<<<dim3(M_ / 4), blk, 0, stream>>>(x, t1, ln1g + l * 256, ln1b + l * 256, x, x_h);

    // cross-attention (banded)
    gemm_h<<<dim3(M_ / 64, 4), blk, 0, stream>>>(
        x_h, wH + O_CAIN + l * 196608, ca_in_b + l * 768, nullptr, Rh, M_, 256, 256, 0);
    gemm_h<<<dim3(M_ / 64, 8), blk, 0, stream>>>(
        audio_h, wH + O_CAIN + l * 196608 + 65536, ca_in_b + l * 768 + 256,
        nullptr, ckv_h, M_, 512, 256, 0);
    cross_attn<<<dim3(M_ * H_ / 256), blk, 0, stream>>>(Rh, ckv_h, att_h);
    gemm_h<<<dim3(M_ / 64, 4), blk, 0, stream>>>(
        att_h, wH + O_CAOUT + l * 65536, ca_out_b + l * 256, t1, nullptr, M_, 256, 256, 0);
    ln_res<<<dim3(M_ / 4), blk, 0, stream>>>(x, t1, ln2g + l * 256, ln2b + l * 256, x, x_h);

    // FFN
    gemm_h<<<dim3(M_ / 64, 8), blk, 0, stream>>>(
        x_h, wH + O_FF1 + l * 131072, ff1b + l * 512, nullptr, Rh, M_, 512, 256, 1);
    gemm_h<<<dim3(M_ / 64, 4), blk, 0, stream>>>(
        Rh, wH + O_FF2 + l * 131072, ff2b + l * 256, t1, nullptr, M_, 256, 512, 0);
    ln_res<<<dim3(M_ / 4), blk, 0, stream>>>(x, t1, ln3g + l * 256, ln3b + l * 256, x, x_h);
  }

  head_mfma<<<dim3(M_ / 64), blk, 0, stream>>>(x_h, wH + O_VR, bvr, out);
}